// Round 1
// baseline (3357.129 us; speedup 1.0000x reference)
//
#include <hip/hip_runtime.h>
#include <math.h>

#define NND 100000
#define NED 800000
#define NLAY 3
static constexpr float LNEPS = 1e-5f;

// ---------------- init: zero deg + reduction accumulators ----------------
__global__ void k_init(int* __restrict__ deg, float* __restrict__ rsum, unsigned* __restrict__ rmax) {
    int gt = blockIdx.x * blockDim.x + threadIdx.x;
    for (int i = gt; i < NND; i += gridDim.x * blockDim.x) deg[i] = 0;
    if (gt < 64) { rsum[gt] = 0.f; rmax[gt] = 0u; }
}

// ---------------- embed: x[n] = table[type[n]] ----------------
__global__ void k_embed(const int* __restrict__ ty, const float4* __restrict__ tab, float4* __restrict__ x) {
    int t = blockIdx.x * blockDim.x + threadIdx.x;  // one float4 per thread
    if (t >= NND * 16) return;
    int n = t >> 4, q = t & 15;
    x[t] = tab[ty[n] * 16 + q];
}

// ---------------- degree histogram ----------------
__global__ void k_hist(const int* __restrict__ e, int* __restrict__ deg) {
    int t = blockIdx.x * blockDim.x + threadIdx.x;
    if (t >= NED) return;
    atomicAdd(&deg[e[2 * t + 1]], 1);
}

// ---------------- scan step 1: per-1024-tile sums ----------------
__global__ void k_bsum(const int* __restrict__ deg, int* __restrict__ bsum) {
    __shared__ int sm[256];
    int base = blockIdx.x * 1024 + threadIdx.x * 4;
    int s = 0;
#pragma unroll
    for (int i = 0; i < 4; i++) { int idx = base + i; if (idx < NND) s += deg[idx]; }
    sm[threadIdx.x] = s; __syncthreads();
    for (int off = 128; off > 0; off >>= 1) {
        if (threadIdx.x < off) sm[threadIdx.x] += sm[threadIdx.x + off];
        __syncthreads();
    }
    if (threadIdx.x == 0) bsum[blockIdx.x] = sm[0];
}

// ---------------- scan step 2: exclusive scan of 98 tile sums ----------------
__global__ void k_bscan(const int* __restrict__ bsum, int* __restrict__ boff, int* __restrict__ row) {
    __shared__ int p[128];
    int t = threadIdx.x;
    int v = (t < 98) ? bsum[t] : 0;
    p[t] = v; __syncthreads();
    for (int off = 1; off < 128; off *= 2) {
        int u = (t >= off) ? p[t - off] : 0;
        __syncthreads();
        p[t] += u;
        __syncthreads();
    }
    if (t < 98) boff[t] = p[t] - v;       // exclusive prefix
    if (t == 127) row[NND] = p[127];      // total = NED
}

// ---------------- scan step 3: per-tile scan + global offset ----------------
__global__ void k_scan3(const int* __restrict__ deg, const int* __restrict__ boff,
                        int* __restrict__ row, int* __restrict__ cur) {
    __shared__ int p[1024];
    int t = threadIdx.x;
    int gi = blockIdx.x * 1024 + t;
    int v = (gi < NND) ? deg[gi] : 0;
    p[t] = v; __syncthreads();
    for (int off = 1; off < 1024; off *= 2) {
        int u = (t >= off) ? p[t - off] : 0;
        __syncthreads();
        p[t] += u;
        __syncthreads();
    }
    if (gi < NND) {
        int ex = boff[blockIdx.x] + p[t] - v;
        row[gi] = ex;
        cur[gi] = ex;
    }
}

// ---------------- scatter srcs into CSR ----------------
__global__ void k_scatter(const int* __restrict__ e, int* __restrict__ cur, int* __restrict__ srcs) {
    int t = blockIdx.x * blockDim.x + threadIdx.x;
    if (t >= NED) return;
    int tg = e[2 * t + 1];
    int pos = atomicAdd(&cur[tg], 1);
    srcs[pos] = e[2 * t];
}

// ---------------- P = x@Ws ; Q = x@Wt + b  (64-node tile, fp32 VALU) ----------------
#define WSTR 516
__global__ __launch_bounds__(256) void k_pq(const float* __restrict__ x, const float* __restrict__ wg,
                                            const float* __restrict__ bg,
                                            float* __restrict__ P, float* __restrict__ Q) {
    __shared__ float xs[64 * 68];
    __shared__ float wl[16 * WSTR];
    int t = threadIdx.x;
    int nbase = blockIdx.x * 64;
    // stage x tile (zero-pad OOB rows)
#pragma unroll
    for (int r = 0; r < 4; r++) {
        int id = t + 256 * r;           // [0,1024) float4 units
        int n = id >> 4, q = id & 15;
        float4 v = make_float4(0.f, 0.f, 0.f, 0.f);
        int gn = nbase + n;
        if (gn < NND) v = *(const float4*)(x + gn * 64 + q * 4);
        *(float4*)(xs + n * 68 + q * 4) = v;
    }
    // stage both W halves in padded col-block layout: wl[c][k][8], stride WSTR
#pragma unroll
    for (int r = 0; r < 8; r++) {
        int id = t + 256 * r;           // [0,2048) float4 units
        int c = id >> 7;
        int rem = id & 127;
        int k = rem >> 1, half = rem & 1;
        int grow = (c < 8) ? k : 64 + k;
        int gcol = (c & 7) * 8 + half * 4;
        float4 v = *(const float4*)(wg + grow * 64 + gcol);
        *(float4*)(wl + c * WSTR + k * 8 + half * 4) = v;
    }
    __syncthreads();
    int c = t & 15, g = t >> 4;
    int n0 = g * 4;
    float acc[4][8];
#pragma unroll
    for (int i = 0; i < 4; i++)
#pragma unroll
        for (int j = 0; j < 8; j++) acc[i][j] = 0.f;
    const float* wbase = wl + c * WSTR;
#pragma unroll
    for (int k4 = 0; k4 < 16; k4++) {
        float xv[4][4];
#pragma unroll
        for (int i = 0; i < 4; i++) {
            float4 tmp = *(const float4*)(xs + (n0 + i) * 68 + k4 * 4);
            xv[i][0] = tmp.x; xv[i][1] = tmp.y; xv[i][2] = tmp.z; xv[i][3] = tmp.w;
        }
#pragma unroll
        for (int kk = 0; kk < 4; kk++) {
            float4 w0 = *(const float4*)(wbase + (k4 * 4 + kk) * 8);
            float4 w1 = *(const float4*)(wbase + (k4 * 4 + kk) * 8 + 4);
            float wv[8] = {w0.x, w0.y, w0.z, w0.w, w1.x, w1.y, w1.z, w1.w};
#pragma unroll
            for (int i = 0; i < 4; i++)
#pragma unroll
                for (int j = 0; j < 8; j++) acc[i][j] += xv[i][kk] * wv[j];
        }
    }
    bool isQ = (c >= 8);
    int j0 = (c & 7) * 8;
    float bj[8];
#pragma unroll
    for (int v = 0; v < 8; v++) bj[v] = isQ ? bg[j0 + v] : 0.f;
    float* outp = isQ ? Q : P;
#pragma unroll
    for (int i = 0; i < 4; i++) {
        int gn = nbase + n0 + i;
        if (gn < NND) {
            float o[8];
#pragma unroll
            for (int j = 0; j < 8; j++) o[j] = acc[i][j] + bj[j];
            *(float4*)(outp + gn * 64 + j0)     = make_float4(o[0], o[1], o[2], o[3]);
            *(float4*)(outp + gn * 64 + j0 + 4) = make_float4(o[4], o[5], o[6], o[7]);
        }
    }
}

// ---------------- aggregation: wave per node, lane per feature ----------------
__global__ __launch_bounds__(256) void k_agg(const float* __restrict__ P, const float* __restrict__ Q,
                                             const int* __restrict__ row, const int* __restrict__ srcs,
                                             float* __restrict__ agg) {
    int wid = (blockIdx.x * blockDim.x + threadIdx.x) >> 6;  // node id
    int lane = threadIdx.x & 63;
    if (wid >= NND) return;
    int beg = row[wid], end = row[wid + 1];
    float qv = Q[wid * 64 + lane];
    float acc = 0.f;
    for (int e0 = beg; e0 < end; e0 += 64) {
        int cnt = min(64, end - e0);
        int sv = (lane < cnt) ? srcs[e0 + lane] : 0;
        for (int i = 0; i < cnt; i++) {
            int s = __shfl(sv, i);
            acc += fmaxf(P[s * 64 + lane] + qv, 0.f);
        }
    }
    float d = (float)(end - beg);
    agg[wid * 64 + lane] = acc / fmaxf(d, 1.f);
}

// ---------------- update: u=relu(x@Wx+agg@Wa+b); x=LN(u+x) ----------------
#define USTR 260
__global__ __launch_bounds__(256) void k_upd(float* __restrict__ x, const float* __restrict__ agg,
                                             const float* __restrict__ wg, const float* __restrict__ ub,
                                             const float* __restrict__ lg, const float* __restrict__ lb) {
    __shared__ float xs[64 * 68];
    __shared__ float as_[64 * 68];
    __shared__ float wx[16 * USTR];
    __shared__ float wa[16 * USTR];
    int t = threadIdx.x;
    int nbase = blockIdx.x * 64;
#pragma unroll
    for (int r = 0; r < 4; r++) {
        int id = t + 256 * r;
        int n = id >> 4, q = id & 15;
        int gn = nbase + n;
        float4 vx = make_float4(0.f, 0.f, 0.f, 0.f), va = vx;
        if (gn < NND) {
            vx = *(const float4*)(x + gn * 64 + q * 4);
            va = *(const float4*)(agg + gn * 64 + q * 4);
        }
        *(float4*)(xs + n * 68 + q * 4) = vx;
        *(float4*)(as_ + n * 68 + q * 4) = va;
    }
#pragma unroll
    for (int r = 0; r < 4; r++) {
        int id = t + 256 * r;            // [0,1024) float4 units per matrix
        int c = id >> 6, k = id & 63;
        *(float4*)(wx + c * USTR + k * 4) = *(const float4*)(wg + k * 64 + c * 4);
        *(float4*)(wa + c * USTR + k * 4) = *(const float4*)(wg + (64 + k) * 64 + c * 4);
    }
    __syncthreads();
    int c = t & 15, g = t >> 4;
    int n0 = g * 4, j0 = c * 4;
    float acc[4][4];
#pragma unroll
    for (int i = 0; i < 4; i++)
#pragma unroll
        for (int j = 0; j < 4; j++) acc[i][j] = 0.f;
    const float* wxb = wx + c * USTR;
    const float* wab = wa + c * USTR;
#pragma unroll
    for (int k4 = 0; k4 < 16; k4++) {
        float xv[4][4], av[4][4];
#pragma unroll
        for (int i = 0; i < 4; i++) {
            float4 tx = *(const float4*)(xs + (n0 + i) * 68 + k4 * 4);
            float4 ta = *(const float4*)(as_ + (n0 + i) * 68 + k4 * 4);
            xv[i][0] = tx.x; xv[i][1] = tx.y; xv[i][2] = tx.z; xv[i][3] = tx.w;
            av[i][0] = ta.x; av[i][1] = ta.y; av[i][2] = ta.z; av[i][3] = ta.w;
        }
#pragma unroll
        for (int kk = 0; kk < 4; kk++) {
            float4 w0 = *(const float4*)(wxb + (k4 * 4 + kk) * 4);
            float4 w1 = *(const float4*)(wab + (k4 * 4 + kk) * 4);
            float wxv[4] = {w0.x, w0.y, w0.z, w0.w};
            float wav[4] = {w1.x, w1.y, w1.z, w1.w};
#pragma unroll
            for (int i = 0; i < 4; i++)
#pragma unroll
                for (int j = 0; j < 4; j++)
                    acc[i][j] += xv[i][kk] * wxv[j] + av[i][kk] * wav[j];
        }
    }
    // epilogue: relu + bias + residual + LayerNorm (row spans 16 lanes)
    float4 ubv = *(const float4*)(ub + j0);
    float4 lgv = *(const float4*)(lg + j0);
    float4 lbv = *(const float4*)(lb + j0);
    float ubj[4] = {ubv.x, ubv.y, ubv.z, ubv.w};
    float lgj[4] = {lgv.x, lgv.y, lgv.z, lgv.w};
    float lbj[4] = {lbv.x, lbv.y, lbv.z, lbv.w};
#pragma unroll
    for (int i = 0; i < 4; i++) {
        int n = n0 + i;
        int gn = nbase + n;
        float h[4];
#pragma unroll
        for (int j = 0; j < 4; j++) {
            float u = fmaxf(acc[i][j] + ubj[j], 0.f);
            h[j] = u + xs[n * 68 + j0 + j];
        }
        float s1 = h[0] + h[1] + h[2] + h[3];
        float s2 = h[0] * h[0] + h[1] * h[1] + h[2] * h[2] + h[3] * h[3];
#pragma unroll
        for (int off = 1; off < 16; off *= 2) {
            s1 += __shfl_xor(s1, off);
            s2 += __shfl_xor(s2, off);
        }
        float mu = s1 * (1.f / 64.f);
        float var = s2 * (1.f / 64.f) - mu * mu;
        float rs = rsqrtf(var + LNEPS);
        if (gn < NND) {
            float4 o;
            o.x = (h[0] - mu) * rs * lgj[0] + lbj[0];
            o.y = (h[1] - mu) * rs * lgj[1] + lbj[1];
            o.z = (h[2] - mu) * rs * lgj[2] + lbj[2];
            o.w = (h[3] - mu) * rs * lgj[3] + lbj[3];
            *(float4*)(x + gn * 64 + j0) = o;
        }
    }
}

// ---------------- final reduce: column mean + max ----------------
__global__ void k_reduce(const float* __restrict__ x, float* __restrict__ rsum, unsigned* __restrict__ rmax) {
    __shared__ float sb[256];
    __shared__ float mb[256];
    int t = threadIdx.x;
    int j = t & 63, g = t >> 6;
    float s = 0.f, m = -3.402823466e38f;
    for (int r = blockIdx.x * 4 + g; r < NND; r += gridDim.x * 4) {
        float v = x[r * 64 + j];
        s += v;
        m = fmaxf(m, v);
    }
    sb[t] = s; mb[t] = m; __syncthreads();
    if (t < 64) {
        s = sb[t] + sb[t + 64] + sb[t + 128] + sb[t + 192];
        m = fmaxf(fmaxf(mb[t], mb[t + 64]), fmaxf(mb[t + 128], mb[t + 192]));
        atomicAdd(&rsum[j], s);
        unsigned b = __float_as_uint(m);
        unsigned enc = (b & 0x80000000u) ? ~b : (b | 0x80000000u);
        atomicMax(&rmax[j], enc);
    }
}

__global__ void k_fin(const float* __restrict__ rsum, const unsigned* __restrict__ rmax, float* __restrict__ out) {
    int t = threadIdx.x;
    if (t < 64) {
        out[t] = rsum[t] * (1.f / (float)NND);
    } else if (t < 128) {
        unsigned u = rmax[t - 64];
        unsigned b = (u & 0x80000000u) ? (u & 0x7fffffffu) : ~u;
        out[t] = __uint_as_float(b);
    }
}

extern "C" void kernel_launch(void* const* d_in, const int* in_sizes, int n_in,
                              void* d_out, int out_size, void* d_ws, size_t ws_size,
                              hipStream_t stream) {
    const int* ty      = (const int*)d_in[0];
    const int* ed      = (const int*)d_in[1];
    const float* tab   = (const float*)d_in[2];
    const float* msg_w = (const float*)d_in[3];
    const float* msg_b = (const float*)d_in[4];
    const float* upd_w = (const float*)d_in[5];
    const float* upd_b = (const float*)d_in[6];
    const float* ln_g  = (const float*)d_in[7];
    const float* ln_b  = (const float*)d_in[8];
    float* out = (float*)d_out;

    char* w = (char*)d_ws;
    auto alloc = [&](size_t sz) { char* p = w; w += (sz + 255) & ~(size_t)255; return p; };
    float* x    = (float*)alloc((size_t)NND * 64 * 4);
    float* P    = (float*)alloc((size_t)NND * 64 * 4);
    float* Q    = (float*)alloc((size_t)NND * 64 * 4);
    float* agg  = (float*)alloc((size_t)NND * 64 * 4);
    int* deg    = (int*)alloc((size_t)NND * 4);
    int* row    = (int*)alloc((size_t)(NND + 1) * 4);
    int* cur    = (int*)alloc((size_t)NND * 4);
    int* srcs   = (int*)alloc((size_t)NED * 4);
    int* bsum   = (int*)alloc(128 * 4);
    int* boff   = (int*)alloc(128 * 4);
    float* rsum = (float*)alloc(64 * 4);
    unsigned* rmax = (unsigned*)alloc(64 * 4);

    k_init<<<256, 256, 0, stream>>>(deg, rsum, rmax);
    k_embed<<<(NND * 16 + 255) / 256, 256, 0, stream>>>(ty, (const float4*)tab, (float4*)x);
    k_hist<<<(NED + 255) / 256, 256, 0, stream>>>(ed, deg);
    k_bsum<<<98, 256, 0, stream>>>(deg, bsum);
    k_bscan<<<1, 128, 0, stream>>>(bsum, boff, row);
    k_scan3<<<98, 1024, 0, stream>>>(deg, boff, row, cur);
    k_scatter<<<(NED + 255) / 256, 256, 0, stream>>>(ed, cur, srcs);

    for (int l = 0; l < NLAY; l++) {
        k_pq<<<(NND + 63) / 64, 256, 0, stream>>>(x, msg_w + (size_t)l * 128 * 64, msg_b + l * 64, P, Q);
        k_agg<<<NND / 4, 256, 0, stream>>>(P, Q, row, srcs, agg);
        k_upd<<<(NND + 63) / 64, 256, 0, stream>>>(x, agg, upd_w + (size_t)l * 128 * 64,
                                                   upd_b + l * 64, ln_g + l * 64, ln_b + l * 64);
    }
    k_reduce<<<256, 256, 0, stream>>>(x, rsum, rmax);
    k_fin<<<1, 128, 0, stream>>>(rsum, rmax, out);
}

// Round 2
// 612.095 us; speedup vs baseline: 5.4847x; 5.4847x over previous
//
#include <hip/hip_runtime.h>
#include <math.h>

#define NND 100000
#define NED 800000
#define NLAY 3
static constexpr float LNEPS = 1e-5f;

// ---------------- init: zero deg + reduction accumulators ----------------
__global__ void k_init(int* __restrict__ deg, float* __restrict__ rsum, unsigned* __restrict__ rmax) {
    int gt = blockIdx.x * blockDim.x + threadIdx.x;
    for (int i = gt; i < NND; i += gridDim.x * blockDim.x) deg[i] = 0;
    if (gt < 64) { rsum[gt] = 0.f; rmax[gt] = 0u; }
}

// ---------------- embed: x[n] = table[type[n]] ----------------
__global__ void k_embed(const int* __restrict__ ty, const float4* __restrict__ tab, float4* __restrict__ x) {
    int t = blockIdx.x * blockDim.x + threadIdx.x;  // one float4 per thread
    if (t >= NND * 16) return;
    int n = t >> 4, q = t & 15;
    x[t] = tab[ty[n] * 16 + q];
}

// ---------------- degree histogram ----------------
__global__ void k_hist(const int* __restrict__ e, int* __restrict__ deg) {
    int t = blockIdx.x * blockDim.x + threadIdx.x;
    if (t >= NED) return;
    atomicAdd(&deg[e[2 * t + 1]], 1);
}

// ---------------- scan step 1: per-1024-tile sums ----------------
__global__ void k_bsum(const int* __restrict__ deg, int* __restrict__ bsum) {
    __shared__ int sm[256];
    int base = blockIdx.x * 1024 + threadIdx.x * 4;
    int s = 0;
#pragma unroll
    for (int i = 0; i < 4; i++) { int idx = base + i; if (idx < NND) s += deg[idx]; }
    sm[threadIdx.x] = s; __syncthreads();
    for (int off = 128; off > 0; off >>= 1) {
        if (threadIdx.x < off) sm[threadIdx.x] += sm[threadIdx.x + off];
        __syncthreads();
    }
    if (threadIdx.x == 0) bsum[blockIdx.x] = sm[0];
}

// ---------------- scan step 2: exclusive scan of 98 tile sums ----------------
__global__ void k_bscan(const int* __restrict__ bsum, int* __restrict__ boff, int* __restrict__ row) {
    __shared__ int p[128];
    int t = threadIdx.x;
    int v = (t < 98) ? bsum[t] : 0;
    p[t] = v; __syncthreads();
    for (int off = 1; off < 128; off *= 2) {
        int u = (t >= off) ? p[t - off] : 0;
        __syncthreads();
        p[t] += u;
        __syncthreads();
    }
    if (t < 98) boff[t] = p[t] - v;       // exclusive prefix
    if (t == 127) row[NND] = p[127];      // total = NED
}

// ---------------- scan step 3: per-tile scan + global offset ----------------
__global__ void k_scan3(const int* __restrict__ deg, const int* __restrict__ boff,
                        int* __restrict__ row, int* __restrict__ cur) {
    __shared__ int p[1024];
    int t = threadIdx.x;
    int gi = blockIdx.x * 1024 + t;
    int v = (gi < NND) ? deg[gi] : 0;
    p[t] = v; __syncthreads();
    for (int off = 1; off < 1024; off *= 2) {
        int u = (t >= off) ? p[t - off] : 0;
        __syncthreads();
        p[t] += u;
        __syncthreads();
    }
    if (gi < NND) {
        int ex = boff[blockIdx.x] + p[t] - v;
        row[gi] = ex;
        cur[gi] = ex;
    }
}

// ---------------- scatter srcs into CSR ----------------
__global__ void k_scatter(const int* __restrict__ e, int* __restrict__ cur, int* __restrict__ srcs) {
    int t = blockIdx.x * blockDim.x + threadIdx.x;
    if (t >= NED) return;
    int tg = e[2 * t + 1];
    int pos = atomicAdd(&cur[tg], 1);
    srcs[pos] = e[2 * t];
}

// ---------------- P = x@Ws ; Q = x@Wt + b  (64-node tile, fp32 VALU) ----------------
// Register-pressure controlled: k-loop NOT unrolled (spill at 256 VGPR was 800MB
// of scratch traffic in round 1). launch_bounds(256,2) caps VGPR at 128.
#define WSTR 516
__global__ __launch_bounds__(256, 2) void k_pq(const float* __restrict__ x, const float* __restrict__ wg,
                                               const float* __restrict__ bg,
                                               float* __restrict__ P, float* __restrict__ Q) {
    __shared__ float xs[64 * 68];
    __shared__ float wl[16 * WSTR];
    int t = threadIdx.x;
    int nbase = blockIdx.x * 64;
    // stage x tile (zero-pad OOB rows)
#pragma unroll
    for (int r = 0; r < 4; r++) {
        int id = t + 256 * r;           // [0,1024) float4 units
        int n = id >> 4, q = id & 15;
        float4 v = make_float4(0.f, 0.f, 0.f, 0.f);
        int gn = nbase + n;
        if (gn < NND) v = *(const float4*)(x + gn * 64 + q * 4);
        *(float4*)(xs + n * 68 + q * 4) = v;
    }
    // stage both W halves in padded col-block layout: wl[c][k][8], stride WSTR
#pragma unroll
    for (int r = 0; r < 8; r++) {
        int id = t + 256 * r;           // [0,2048) float4 units
        int c = id >> 7;
        int rem = id & 127;
        int k = rem >> 1, half = rem & 1;
        int grow = (c < 8) ? k : 64 + k;
        int gcol = (c & 7) * 8 + half * 4;
        float4 v = *(const float4*)(wg + grow * 64 + gcol);
        *(float4*)(wl + c * WSTR + k * 8 + half * 4) = v;
    }
    __syncthreads();
    int c = t & 15, g = t >> 4;
    int n0 = g * 4;
    float acc[4][8];
#pragma unroll
    for (int i = 0; i < 4; i++)
#pragma unroll
        for (int j = 0; j < 8; j++) acc[i][j] = 0.f;
    const float* wbase = wl + c * WSTR;
#pragma unroll 1
    for (int k4 = 0; k4 < 16; k4++) {
        float xv[4][4];
#pragma unroll
        for (int i = 0; i < 4; i++) {
            float4 tmp = *(const float4*)(xs + (n0 + i) * 68 + k4 * 4);
            xv[i][0] = tmp.x; xv[i][1] = tmp.y; xv[i][2] = tmp.z; xv[i][3] = tmp.w;
        }
#pragma unroll
        for (int kk = 0; kk < 4; kk++) {
            float4 w0 = *(const float4*)(wbase + (k4 * 4 + kk) * 8);
            float4 w1 = *(const float4*)(wbase + (k4 * 4 + kk) * 8 + 4);
            float wv[8] = {w0.x, w0.y, w0.z, w0.w, w1.x, w1.y, w1.z, w1.w};
#pragma unroll
            for (int i = 0; i < 4; i++)
#pragma unroll
                for (int j = 0; j < 8; j++) acc[i][j] += xv[i][kk] * wv[j];
        }
    }
    bool isQ = (c >= 8);
    int j0 = (c & 7) * 8;
    float bj[8];
#pragma unroll
    for (int v = 0; v < 8; v++) bj[v] = isQ ? bg[j0 + v] : 0.f;
    float* outp = isQ ? Q : P;
#pragma unroll
    for (int i = 0; i < 4; i++) {
        int gn = nbase + n0 + i;
        if (gn < NND) {
            float o[8];
#pragma unroll
            for (int j = 0; j < 8; j++) o[j] = acc[i][j] + bj[j];
            *(float4*)(outp + gn * 64 + j0)     = make_float4(o[0], o[1], o[2], o[3]);
            *(float4*)(outp + gn * 64 + j0 + 4) = make_float4(o[4], o[5], o[6], o[7]);
        }
    }
}

// ---------------- aggregation: wave per node, lane per feature ----------------
__global__ __launch_bounds__(256) void k_agg(const float* __restrict__ P, const float* __restrict__ Q,
                                             const int* __restrict__ row, const int* __restrict__ srcs,
                                             float* __restrict__ agg) {
    int wid = (blockIdx.x * blockDim.x + threadIdx.x) >> 6;  // node id
    int lane = threadIdx.x & 63;
    if (wid >= NND) return;
    int beg = row[wid], end = row[wid + 1];
    float qv = Q[wid * 64 + lane];
    float acc = 0.f;
    for (int e0 = beg; e0 < end; e0 += 64) {
        int cnt = min(64, end - e0);
        int sv = (lane < cnt) ? srcs[e0 + lane] : 0;
        for (int i = 0; i < cnt; i++) {
            int s = __shfl(sv, i);
            acc += fmaxf(P[s * 64 + lane] + qv, 0.f);
        }
    }
    float d = (float)(end - beg);
    agg[wid * 64 + lane] = acc / fmaxf(d, 1.f);
}

// ---------------- update: u=relu(x@Wx+agg@Wa+b); x=LN(u+x) ----------------
#define USTR 260
__global__ __launch_bounds__(256, 2) void k_upd(float* __restrict__ x, const float* __restrict__ agg,
                                                const float* __restrict__ wg, const float* __restrict__ ub,
                                                const float* __restrict__ lg, const float* __restrict__ lb) {
    __shared__ float xs[64 * 68];
    __shared__ float as_[64 * 68];
    __shared__ float wx[16 * USTR];
    __shared__ float wa[16 * USTR];
    int t = threadIdx.x;
    int nbase = blockIdx.x * 64;
#pragma unroll
    for (int r = 0; r < 4; r++) {
        int id = t + 256 * r;
        int n = id >> 4, q = id & 15;
        int gn = nbase + n;
        float4 vx = make_float4(0.f, 0.f, 0.f, 0.f), va = vx;
        if (gn < NND) {
            vx = *(const float4*)(x + gn * 64 + q * 4);
            va = *(const float4*)(agg + gn * 64 + q * 4);
        }
        *(float4*)(xs + n * 68 + q * 4) = vx;
        *(float4*)(as_ + n * 68 + q * 4) = va;
    }
#pragma unroll
    for (int r = 0; r < 4; r++) {
        int id = t + 256 * r;            // [0,1024) float4 units per matrix
        int c = id >> 6, k = id & 63;
        *(float4*)(wx + c * USTR + k * 4) = *(const float4*)(wg + k * 64 + c * 4);
        *(float4*)(wa + c * USTR + k * 4) = *(const float4*)(wg + (64 + k) * 64 + c * 4);
    }
    __syncthreads();
    int c = t & 15, g = t >> 4;
    int n0 = g * 4, j0 = c * 4;
    float acc[4][4];
#pragma unroll
    for (int i = 0; i < 4; i++)
#pragma unroll
        for (int j = 0; j < 4; j++) acc[i][j] = 0.f;
    const float* wxb = wx + c * USTR;
    const float* wab = wa + c * USTR;
#pragma unroll 1
    for (int k4 = 0; k4 < 16; k4++) {
        float xv[4][4], av[4][4];
#pragma unroll
        for (int i = 0; i < 4; i++) {
            float4 tx = *(const float4*)(xs + (n0 + i) * 68 + k4 * 4);
            float4 ta = *(const float4*)(as_ + (n0 + i) * 68 + k4 * 4);
            xv[i][0] = tx.x; xv[i][1] = tx.y; xv[i][2] = tx.z; xv[i][3] = tx.w;
            av[i][0] = ta.x; av[i][1] = ta.y; av[i][2] = ta.z; av[i][3] = ta.w;
        }
#pragma unroll
        for (int kk = 0; kk < 4; kk++) {
            float4 w0 = *(const float4*)(wxb + (k4 * 4 + kk) * 4);
            float4 w1 = *(const float4*)(wab + (k4 * 4 + kk) * 4);
            float wxv[4] = {w0.x, w0.y, w0.z, w0.w};
            float wav[4] = {w1.x, w1.y, w1.z, w1.w};
#pragma unroll
            for (int i = 0; i < 4; i++)
#pragma unroll
                for (int j = 0; j < 4; j++)
                    acc[i][j] += xv[i][kk] * wxv[j] + av[i][kk] * wav[j];
        }
    }
    // epilogue: relu + bias + residual + LayerNorm (row spans 16 lanes)
    float4 ubv = *(const float4*)(ub + j0);
    float4 lgv = *(const float4*)(lg + j0);
    float4 lbv = *(const float4*)(lb + j0);
    float ubj[4] = {ubv.x, ubv.y, ubv.z, ubv.w};
    float lgj[4] = {lgv.x, lgv.y, lgv.z, lgv.w};
    float lbj[4] = {lbv.x, lbv.y, lbv.z, lbv.w};
#pragma unroll
    for (int i = 0; i < 4; i++) {
        int n = n0 + i;
        int gn = nbase + n;
        float h[4];
#pragma unroll
        for (int j = 0; j < 4; j++) {
            float u = fmaxf(acc[i][j] + ubj[j], 0.f);
            h[j] = u + xs[n * 68 + j0 + j];
        }
        float s1 = h[0] + h[1] + h[2] + h[3];
        float s2 = h[0] * h[0] + h[1] * h[1] + h[2] * h[2] + h[3] * h[3];
#pragma unroll
        for (int off = 1; off < 16; off *= 2) {
            s1 += __shfl_xor(s1, off);
            s2 += __shfl_xor(s2, off);
        }
        float mu = s1 * (1.f / 64.f);
        float var = s2 * (1.f / 64.f) - mu * mu;
        float rs = rsqrtf(var + LNEPS);
        if (gn < NND) {
            float4 o;
            o.x = (h[0] - mu) * rs * lgj[0] + lbj[0];
            o.y = (h[1] - mu) * rs * lgj[1] + lbj[1];
            o.z = (h[2] - mu) * rs * lgj[2] + lbj[2];
            o.w = (h[3] - mu) * rs * lgj[3] + lbj[3];
            *(float4*)(x + gn * 64 + j0) = o;
        }
    }
}

// ---------------- final reduce: column mean + max ----------------
__global__ void k_reduce(const float* __restrict__ x, float* __restrict__ rsum, unsigned* __restrict__ rmax) {
    __shared__ float sb[256];
    __shared__ float mb[256];
    int t = threadIdx.x;
    int j = t & 63, g = t >> 6;
    float s = 0.f, m = -3.402823466e38f;
    for (int r = blockIdx.x * 4 + g; r < NND; r += gridDim.x * 4) {
        float v = x[r * 64 + j];
        s += v;
        m = fmaxf(m, v);
    }
    sb[t] = s; mb[t] = m; __syncthreads();
    if (t < 64) {
        s = sb[t] + sb[t + 64] + sb[t + 128] + sb[t + 192];
        m = fmaxf(fmaxf(mb[t], mb[t + 64]), fmaxf(mb[t + 128], mb[t + 192]));
        atomicAdd(&rsum[j], s);
        unsigned b = __float_as_uint(m);
        unsigned enc = (b & 0x80000000u) ? ~b : (b | 0x80000000u);
        atomicMax(&rmax[j], enc);
    }
}

__global__ void k_fin(const float* __restrict__ rsum, const unsigned* __restrict__ rmax, float* __restrict__ out) {
    int t = threadIdx.x;
    if (t < 64) {
        out[t] = rsum[t] * (1.f / (float)NND);
    } else if (t < 128) {
        unsigned u = rmax[t - 64];
        unsigned b = (u & 0x80000000u) ? (u & 0x7fffffffu) : ~u;
        out[t] = __uint_as_float(b);
    }
}

extern "C" void kernel_launch(void* const* d_in, const int* in_sizes, int n_in,
                              void* d_out, int out_size, void* d_ws, size_t ws_size,
                              hipStream_t stream) {
    const int* ty      = (const int*)d_in[0];
    const int* ed      = (const int*)d_in[1];
    const float* tab   = (const float*)d_in[2];
    const float* msg_w = (const float*)d_in[3];
    const float* msg_b = (const float*)d_in[4];
    const float* upd_w = (const float*)d_in[5];
    const float* upd_b = (const float*)d_in[6];
    const float* ln_g  = (const float*)d_in[7];
    const float* ln_b  = (const float*)d_in[8];
    float* out = (float*)d_out;

    char* w = (char*)d_ws;
    auto alloc = [&](size_t sz) { char* p = w; w += (sz + 255) & ~(size_t)255; return p; };
    float* x    = (float*)alloc((size_t)NND * 64 * 4);
    float* P    = (float*)alloc((size_t)NND * 64 * 4);
    float* Q    = (float*)alloc((size_t)NND * 64 * 4);
    float* agg  = (float*)alloc((size_t)NND * 64 * 4);
    int* deg    = (int*)alloc((size_t)NND * 4);
    int* row    = (int*)alloc((size_t)(NND + 1) * 4);
    int* cur    = (int*)alloc((size_t)NND * 4);
    int* srcs   = (int*)alloc((size_t)NED * 4);
    int* bsum   = (int*)alloc(128 * 4);
    int* boff   = (int*)alloc(128 * 4);
    float* rsum = (float*)alloc(64 * 4);
    unsigned* rmax = (unsigned*)alloc(64 * 4);

    k_init<<<256, 256, 0, stream>>>(deg, rsum, rmax);
    k_embed<<<(NND * 16 + 255) / 256, 256, 0, stream>>>(ty, (const float4*)tab, (float4*)x);
    k_hist<<<(NED + 255) / 256, 256, 0, stream>>>(ed, deg);
    k_bsum<<<98, 256, 0, stream>>>(deg, bsum);
    k_bscan<<<1, 128, 0, stream>>>(bsum, boff, row);
    k_scan3<<<98, 1024, 0, stream>>>(deg, boff, row, cur);
    k_scatter<<<(NED + 255) / 256, 256, 0, stream>>>(ed, cur, srcs);

    for (int l = 0; l < NLAY; l++) {
        k_pq<<<(NND + 63) / 64, 256, 0, stream>>>(x, msg_w + (size_t)l * 128 * 64, msg_b + l * 64, P, Q);
        k_agg<<<NND / 4, 256, 0, stream>>>(P, Q, row, srcs, agg);
        k_upd<<<(NND + 63) / 64, 256, 0, stream>>>(x, agg, upd_w + (size_t)l * 128 * 64,
                                                   upd_b + l * 64, ln_g + l * 64, ln_b + l * 64);
    }
    k_reduce<<<256, 256, 0, stream>>>(x, rsum, rmax);
    k_fin<<<1, 128, 0, stream>>>(rsum, rmax, out);
}

// Round 3
// 452.993 us; speedup vs baseline: 7.4110x; 1.3512x over previous
//
#include <hip/hip_runtime.h>
#include <hip/hip_fp16.h>
#include <math.h>

#define NND 100000
#define NED 800000
#define NLAY 3
static constexpr float LNEPS = 1e-5f;

typedef __attribute__((ext_vector_type(8))) short short8;
typedef __attribute__((ext_vector_type(4))) float floatx4;

// fp32 -> bf16 round-to-nearest-even
__device__ __forceinline__ short f2bf(float f) {
    unsigned u = __float_as_uint(f);
    u += 0x7fffu + ((u >> 16) & 1u);
    return (short)(u >> 16);
}

// ---------------- init: zero deg + reduction accumulators ----------------
__global__ void k_init(int* __restrict__ deg, float* __restrict__ rsum, unsigned* __restrict__ rmax) {
    int gt = blockIdx.x * blockDim.x + threadIdx.x;
    for (int i = gt; i < NND; i += gridDim.x * blockDim.x) deg[i] = 0;
    if (gt < 64) { rsum[gt] = 0.f; rmax[gt] = 0u; }
}

// ---------------- embed: x[n] = table[type[n]] ----------------
__global__ void k_embed(const int* __restrict__ ty, const float4* __restrict__ tab, float4* __restrict__ x) {
    int t = blockIdx.x * blockDim.x + threadIdx.x;  // one float4 per thread
    if (t >= NND * 16) return;
    int n = t >> 4, q = t & 15;
    x[t] = tab[ty[n] * 16 + q];
}

// ---------------- degree histogram ----------------
__global__ void k_hist(const int* __restrict__ e, int* __restrict__ deg) {
    int t = blockIdx.x * blockDim.x + threadIdx.x;
    if (t >= NED) return;
    atomicAdd(&deg[e[2 * t + 1]], 1);
}

// ---------------- scan step 1: per-1024-tile sums ----------------
__global__ void k_bsum(const int* __restrict__ deg, int* __restrict__ bsum) {
    __shared__ int sm[256];
    int base = blockIdx.x * 1024 + threadIdx.x * 4;
    int s = 0;
#pragma unroll
    for (int i = 0; i < 4; i++) { int idx = base + i; if (idx < NND) s += deg[idx]; }
    sm[threadIdx.x] = s; __syncthreads();
    for (int off = 128; off > 0; off >>= 1) {
        if (threadIdx.x < off) sm[threadIdx.x] += sm[threadIdx.x + off];
        __syncthreads();
    }
    if (threadIdx.x == 0) bsum[blockIdx.x] = sm[0];
}

// ---------------- scan step 2: exclusive scan of 98 tile sums ----------------
__global__ void k_bscan(const int* __restrict__ bsum, int* __restrict__ boff, int* __restrict__ row) {
    __shared__ int p[128];
    int t = threadIdx.x;
    int v = (t < 98) ? bsum[t] : 0;
    p[t] = v; __syncthreads();
    for (int off = 1; off < 128; off *= 2) {
        int u = (t >= off) ? p[t - off] : 0;
        __syncthreads();
        p[t] += u;
        __syncthreads();
    }
    if (t < 98) boff[t] = p[t] - v;       // exclusive prefix
    if (t == 127) row[NND] = p[127];      // total = NED
}

// ---------------- scan step 3: per-tile scan + global offset ----------------
__global__ void k_scan3(const int* __restrict__ deg, const int* __restrict__ boff,
                        int* __restrict__ row, int* __restrict__ cur) {
    __shared__ int p[1024];
    int t = threadIdx.x;
    int gi = blockIdx.x * 1024 + t;
    int v = (gi < NND) ? deg[gi] : 0;
    p[t] = v; __syncthreads();
    for (int off = 1; off < 1024; off *= 2) {
        int u = (t >= off) ? p[t - off] : 0;
        __syncthreads();
        p[t] += u;
        __syncthreads();
    }
    if (gi < NND) {
        int ex = boff[blockIdx.x] + p[t] - v;
        row[gi] = ex;
        cur[gi] = ex;
    }
}

// ---------------- scatter srcs into CSR ----------------
__global__ void k_scatter(const int* __restrict__ e, int* __restrict__ cur, int* __restrict__ srcs) {
    int t = blockIdx.x * blockDim.x + threadIdx.x;
    if (t >= NED) return;
    int tg = e[2 * t + 1];
    int pos = atomicAdd(&cur[tg], 1);
    srcs[pos] = e[2 * t];
}

// ---------------- prep: pre-swizzle weights into MFMA B-fragment layout (bf16) ----------------
// B-frag layout (16x16x32): lane holds B[k=quad*8+j][n=lane&15]; linear = ((tile)*64+lane)*8+j
// msg: K=64,N=128 -> tile = nt*2+ks (nt 0..7, ks 0..1); cols n<64 -> P (W rows 0-63), n>=64 -> Q (W rows 64-127)
// upd: K=128,N=64 -> tile = nt*4+ks (nt 0..3, ks 0..3)
__global__ void k_prep(const float* __restrict__ msg_w, const float* __restrict__ upd_w,
                       short* __restrict__ wmsg, short* __restrict__ wupd) {
    int t = blockIdx.x * blockDim.x + threadIdx.x;
    if (t >= 2 * NLAY * 8192) return;
    int which = t / (NLAY * 8192);
    int e = t % (NLAY * 8192);
    int l = e >> 13, idx = e & 8191;
    int j = idx & 7, lane = (idx >> 3) & 63, hi = idx >> 9;
    int lm = lane & 15, quad = lane >> 4;
    if (which == 0) {
        int ks = hi & 1, nt = hi >> 1;
        int n = nt * 16 + lm, k = ks * 32 + quad * 8 + j;
        float v = (n < 64) ? msg_w[(size_t)l * 8192 + k * 64 + n]
                           : msg_w[(size_t)l * 8192 + (64 + k) * 64 + (n - 64)];
        wmsg[e] = f2bf(v);
    } else {
        int ks = hi & 3, nt = hi >> 2;
        int n = nt * 16 + lm, k = ks * 32 + quad * 8 + j;
        wupd[e] = f2bf(upd_w[(size_t)l * 8192 + k * 64 + n]);
    }
}

// ---------------- P16 = half(x@Ws) ; Q = x@Wt + b  (MFMA, wave = 16 nodes x 128 cols) ----------------
__global__ __launch_bounds__(256) void k_pq(const float* __restrict__ x, const short* __restrict__ wb,
                                            const float* __restrict__ bg,
                                            __half* __restrict__ P16, float* __restrict__ Q) {
    int wv = threadIdx.x >> 6, lane = threadIdx.x & 63;
    int lm = lane & 15, quad = lane >> 4;
    int gmbase = blockIdx.x * 64 + wv * 16;
    int m = gmbase + lm;
    // A-frags: x[m][k], k = ks*32 + quad*8 + j
    short8 a[2];
#pragma unroll
    for (int ks = 0; ks < 2; ks++) {
        float xv[8];
        if (m < NND) {
            float4 v0 = *(const float4*)(x + (size_t)m * 64 + ks * 32 + quad * 8);
            float4 v1 = *(const float4*)(x + (size_t)m * 64 + ks * 32 + quad * 8 + 4);
            xv[0] = v0.x; xv[1] = v0.y; xv[2] = v0.z; xv[3] = v0.w;
            xv[4] = v1.x; xv[5] = v1.y; xv[6] = v1.z; xv[7] = v1.w;
        } else {
#pragma unroll
            for (int j = 0; j < 8; j++) xv[j] = 0.f;
        }
        short8 av;
#pragma unroll
        for (int j = 0; j < 8; j++) av[j] = f2bf(xv[j]);
        a[ks] = av;
    }
    floatx4 acc[8];
#pragma unroll
    for (int nt = 0; nt < 8; nt++) acc[nt] = (floatx4){0.f, 0.f, 0.f, 0.f};
#pragma unroll
    for (int nt = 0; nt < 8; nt++) {
        short8 b0 = *(const short8*)(wb + (size_t)((nt * 2 + 0) * 64 + lane) * 8);
        short8 b1 = *(const short8*)(wb + (size_t)((nt * 2 + 1) * 64 + lane) * 8);
        acc[nt] = __builtin_amdgcn_mfma_f32_16x16x32_bf16(a[0], b0, acc[nt], 0, 0, 0);
        acc[nt] = __builtin_amdgcn_mfma_f32_16x16x32_bf16(a[1], b1, acc[nt], 0, 0, 0);
    }
    float bq[4];
#pragma unroll
    for (int nt = 0; nt < 4; nt++) bq[nt] = bg[nt * 16 + lm];
    // C/D: col = nt*16 + (lane&15), row = quad*4 + reg
#pragma unroll
    for (int reg = 0; reg < 4; reg++) {
        int gn = gmbase + quad * 4 + reg;
        if (gn < NND) {
#pragma unroll
            for (int nt = 0; nt < 4; nt++)
                P16[(size_t)gn * 64 + nt * 16 + lm] = __float2half(acc[nt][reg]);
#pragma unroll
            for (int nt = 4; nt < 8; nt++)
                Q[(size_t)gn * 64 + (nt - 4) * 16 + lm] = acc[nt][reg] + bq[nt - 4];
        }
    }
}

// ---------------- aggregation: wave per node, 2 edges/iter, fp16 P gather ----------------
__global__ __launch_bounds__(256) void k_agg(const __half* __restrict__ P16, const float* __restrict__ Q,
                                             const int* __restrict__ row, const int* __restrict__ srcs,
                                             float* __restrict__ agg) {
    int wid = (blockIdx.x * blockDim.x + threadIdx.x) >> 6;  // node id
    int lane = threadIdx.x & 63;
    if (wid >= NND) return;
    int sub = lane >> 5, f2 = lane & 31, j0 = 2 * f2;
    int beg = row[wid], end = row[wid + 1];
    float2 q = *(const float2*)(Q + (size_t)wid * 64 + j0);
    float a0 = 0.f, a1 = 0.f;
    for (int e0 = beg; e0 < end; e0 += 64) {
        int cnt = min(64, end - e0);
        int sv = (lane < cnt) ? srcs[e0 + lane] : 0;
        int pairs = (cnt + 1) >> 1;
        for (int i = 0; i < pairs; i++) {
            int ei = 2 * i + sub;
            if (ei < cnt) {
                int s = __shfl(sv, ei);
                __half2 hp = *(const __half2*)(P16 + (size_t)s * 64 + j0);
                float2 f = __half22float2(hp);
                a0 += fmaxf(f.x + q.x, 0.f);
                a1 += fmaxf(f.y + q.y, 0.f);
            }
        }
    }
    a0 += __shfl_xor(a0, 32);
    a1 += __shfl_xor(a1, 32);
    if (sub == 0) {
        float inv = 1.f / fmaxf((float)(end - beg), 1.f);
        *(float2*)(agg + (size_t)wid * 64 + j0) = make_float2(a0 * inv, a1 * inv);
    }
}

// ---------------- update: u=relu([x|agg]@W+b); x=LN(u+x)  (MFMA, wave = 16 nodes) ----------------
__global__ __launch_bounds__(256) void k_upd(float* __restrict__ x, const float* __restrict__ agg,
                                             const short* __restrict__ wb, const float* __restrict__ ub,
                                             const float* __restrict__ lg, const float* __restrict__ lb) {
    int wv = threadIdx.x >> 6, lane = threadIdx.x & 63;
    int lm = lane & 15, quad = lane >> 4;
    int gmbase = blockIdx.x * 64 + wv * 16;
    int m = gmbase + lm;
    // A-frags: ks 0,1 from x; ks 2,3 from agg
    short8 a[4];
#pragma unroll
    for (int ks = 0; ks < 4; ks++) {
        const float* src = (ks < 2) ? x : agg;
        int c0 = (ks & 1) * 32 + quad * 8;
        float xv[8];
        if (m < NND) {
            float4 v0 = *(const float4*)(src + (size_t)m * 64 + c0);
            float4 v1 = *(const float4*)(src + (size_t)m * 64 + c0 + 4);
            xv[0] = v0.x; xv[1] = v0.y; xv[2] = v0.z; xv[3] = v0.w;
            xv[4] = v1.x; xv[5] = v1.y; xv[6] = v1.z; xv[7] = v1.w;
        } else {
#pragma unroll
            for (int j = 0; j < 8; j++) xv[j] = 0.f;
        }
        short8 av;
#pragma unroll
        for (int j = 0; j < 8; j++) av[j] = f2bf(xv[j]);
        a[ks] = av;
    }
    floatx4 acc[4];
#pragma unroll
    for (int nt = 0; nt < 4; nt++) acc[nt] = (floatx4){0.f, 0.f, 0.f, 0.f};
#pragma unroll
    for (int nt = 0; nt < 4; nt++) {
#pragma unroll
        for (int ks = 0; ks < 4; ks++) {
            short8 b = *(const short8*)(wb + (size_t)((nt * 4 + ks) * 64 + lane) * 8);
            acc[nt] = __builtin_amdgcn_mfma_f32_16x16x32_bf16(a[ks], b, acc[nt], 0, 0, 0);
        }
    }
    float ubv[4], lgv[4], lbv[4];
#pragma unroll
    for (int nt = 0; nt < 4; nt++) {
        int col = nt * 16 + lm;
        ubv[nt] = ub[col]; lgv[nt] = lg[col]; lbv[nt] = lb[col];
    }
    // epilogue per C-row: relu+bias, residual (fp32 x re-read), LN across the 16 lanes of the quad
#pragma unroll
    for (int reg = 0; reg < 4; reg++) {
        int gn = gmbase + quad * 4 + reg;
        bool ok = gn < NND;
        float h[4];
#pragma unroll
        for (int nt = 0; nt < 4; nt++) {
            float xv = ok ? x[(size_t)gn * 64 + nt * 16 + lm] : 0.f;
            float u = fmaxf(acc[nt][reg] + ubv[nt], 0.f);
            h[nt] = u + xv;
        }
        float s1 = h[0] + h[1] + h[2] + h[3];
        float s2 = h[0] * h[0] + h[1] * h[1] + h[2] * h[2] + h[3] * h[3];
#pragma unroll
        for (int off = 1; off < 16; off *= 2) {
            s1 += __shfl_xor(s1, off);
            s2 += __shfl_xor(s2, off);
        }
        float mu = s1 * (1.f / 64.f);
        float var = s2 * (1.f / 64.f) - mu * mu;
        float rs = rsqrtf(var + LNEPS);
        if (ok) {
#pragma unroll
            for (int nt = 0; nt < 4; nt++)
                x[(size_t)gn * 64 + nt * 16 + lm] = (h[nt] - mu) * rs * lgv[nt] + lbv[nt];
        }
    }
}

// ---------------- final reduce: column mean + max ----------------
__global__ void k_reduce(const float* __restrict__ x, float* __restrict__ rsum, unsigned* __restrict__ rmax) {
    __shared__ float sb[256];
    __shared__ float mb[256];
    int t = threadIdx.x;
    int j = t & 63, g = t >> 6;
    float s = 0.f, m = -3.402823466e38f;
    for (int r = blockIdx.x * 4 + g; r < NND; r += gridDim.x * 4) {
        float v = x[r * 64 + j];
        s += v;
        m = fmaxf(m, v);
    }
    sb[t] = s; mb[t] = m; __syncthreads();
    if (t < 64) {
        s = sb[t] + sb[t + 64] + sb[t + 128] + sb[t + 192];
        m = fmaxf(fmaxf(mb[t], mb[t + 64]), fmaxf(mb[t + 128], mb[t + 192]));
        atomicAdd(&rsum[j], s);
        unsigned b = __float_as_uint(m);
        unsigned enc = (b & 0x80000000u) ? ~b : (b | 0x80000000u);
        atomicMax(&rmax[j], enc);
    }
}

__global__ void k_fin(const float* __restrict__ rsum, const unsigned* __restrict__ rmax, float* __restrict__ out) {
    int t = threadIdx.x;
    if (t < 64) {
        out[t] = rsum[t] * (1.f / (float)NND);
    } else if (t < 128) {
        unsigned u = rmax[t - 64];
        unsigned b = (u & 0x80000000u) ? (u & 0x7fffffffu) : ~u;
        out[t] = __uint_as_float(b);
    }
}

extern "C" void kernel_launch(void* const* d_in, const int* in_sizes, int n_in,
                              void* d_out, int out_size, void* d_ws, size_t ws_size,
                              hipStream_t stream) {
    const int* ty      = (const int*)d_in[0];
    const int* ed      = (const int*)d_in[1];
    const float* tab   = (const float*)d_in[2];
    const float* msg_w = (const float*)d_in[3];
    const float* msg_b = (const float*)d_in[4];
    const float* upd_w = (const float*)d_in[5];
    const float* upd_b = (const float*)d_in[6];
    const float* ln_g  = (const float*)d_in[7];
    const float* ln_b  = (const float*)d_in[8];
    float* out = (float*)d_out;

    char* w = (char*)d_ws;
    auto alloc = [&](size_t sz) { char* p = w; w += (sz + 255) & ~(size_t)255; return p; };
    float* x      = (float*)alloc((size_t)NND * 64 * 4);
    float* Q      = (float*)alloc((size_t)NND * 64 * 4);
    float* agg    = (float*)alloc((size_t)NND * 64 * 4);
    __half* P16   = (__half*)alloc((size_t)NND * 64 * 2);
    int* deg      = (int*)alloc((size_t)NND * 4);
    int* row      = (int*)alloc((size_t)(NND + 1) * 4);
    int* cur      = (int*)alloc((size_t)NND * 4);
    int* srcs     = (int*)alloc((size_t)NED * 4);
    int* bsum     = (int*)alloc(128 * 4);
    int* boff     = (int*)alloc(128 * 4);
    float* rsum   = (float*)alloc(64 * 4);
    unsigned* rmax = (unsigned*)alloc(64 * 4);
    short* wmsg   = (short*)alloc((size_t)NLAY * 8192 * 2);
    short* wupd   = (short*)alloc((size_t)NLAY * 8192 * 2);

    k_init<<<256, 256, 0, stream>>>(deg, rsum, rmax);
    k_prep<<<(2 * NLAY * 8192 + 255) / 256, 256, 0, stream>>>(msg_w, upd_w, wmsg, wupd);
    k_embed<<<(NND * 16 + 255) / 256, 256, 0, stream>>>(ty, (const float4*)tab, (float4*)x);
    k_hist<<<(NED + 255) / 256, 256, 0, stream>>>(ed, deg);
    k_bsum<<<98, 256, 0, stream>>>(deg, bsum);
    k_bscan<<<1, 128, 0, stream>>>(bsum, boff, row);
    k_scan3<<<98, 1024, 0, stream>>>(deg, boff, row, cur);
    k_scatter<<<(NED + 255) / 256, 256, 0, stream>>>(ed, cur, srcs);

    for (int l = 0; l < NLAY; l++) {
        k_pq<<<(NND + 63) / 64, 256, 0, stream>>>(x, wmsg + (size_t)l * 8192, msg_b + l * 64, P16, Q);
        k_agg<<<NND / 4, 256, 0, stream>>>(P16, Q, row, srcs, agg);
        k_upd<<<(NND + 63) / 64, 256, 0, stream>>>(x, agg, wupd + (size_t)l * 8192,
                                                   upd_b + l * 64, ln_g + l * 64, ln_b + l * 64);
    }
    k_reduce<<<256, 256, 0, stream>>>(x, rsum, rmax);
    k_fin<<<1, 128, 0, stream>>>(rsum, rmax, out);
}

// Round 4
// 390.558 us; speedup vs baseline: 8.5957x; 1.1599x over previous
//
#include <hip/hip_runtime.h>
#include <hip/hip_fp16.h>
#include <math.h>

#define NND 100000
#define NED 800000
#define NLAY 3
#define BSH 9                      // 512 nodes per bucket
#define NBKT ((NND + 511) / 512)   // 196
static constexpr float LNEPS = 1e-5f;

typedef __attribute__((ext_vector_type(8))) short short8;
typedef __attribute__((ext_vector_type(4))) float floatx4;

// fp32 -> bf16 round-to-nearest-even
__device__ __forceinline__ short f2bf(float f) {
    unsigned u = __float_as_uint(f);
    u += 0x7fffu + ((u >> 16) & 1u);
    return (short)(u >> 16);
}

// ---------------- init: zero bucket counts + reduction accumulators ----------------
__global__ void k_init(int* __restrict__ bcnt, float* __restrict__ rsum, unsigned* __restrict__ rmax) {
    int gt = blockIdx.x * blockDim.x + threadIdx.x;
    if (gt < NBKT) bcnt[gt] = 0;
    if (gt >= 256 && gt < 320) { rsum[gt - 256] = 0.f; rmax[gt - 256] = 0u; }
}

// ---------------- embed: x[n] = table[type[n]] ----------------
__global__ void k_embed(const int* __restrict__ ty, const float4* __restrict__ tab, float4* __restrict__ x) {
    int t = blockIdx.x * blockDim.x + threadIdx.x;  // one float4 per thread
    if (t >= NND * 16) return;
    int n = t >> 4, q = t & 15;
    x[t] = tab[ty[n] * 16 + q];
}

// ---------------- bucket histogram (LDS-staged, no random global atomics) ----------------
__global__ __launch_bounds__(256) void k_bhist(const int2* __restrict__ e, int* __restrict__ bcnt) {
    __shared__ int h[NBKT];
    for (int i = threadIdx.x; i < NBKT; i += 256) h[i] = 0;
    __syncthreads();
    int stride = gridDim.x * 256;
    for (int i = blockIdx.x * 256 + threadIdx.x; i < NED; i += stride)
        atomicAdd(&h[((unsigned)e[i].y) >> BSH], 1);
    __syncthreads();
    for (int i = threadIdx.x; i < NBKT; i += 256) if (h[i]) atomicAdd(&bcnt[i], h[i]);
}

// ---------------- scan bucket counts -> bucket bases + global tails ----------------
__global__ void k_bbase(const int* __restrict__ bcnt, int* __restrict__ bbase, int* __restrict__ gtail) {
    __shared__ int p[256];
    int t = threadIdx.x;
    int v = (t < NBKT) ? bcnt[t] : 0;
    p[t] = v; __syncthreads();
    for (int off = 1; off < 256; off <<= 1) {
        int u = (t >= off) ? p[t - off] : 0;
        __syncthreads();
        p[t] += u; __syncthreads();
    }
    if (t < NBKT) { int ex = p[t] - v; bbase[t] = ex; gtail[t] = ex; }
    if (t == NBKT - 1) bbase[NBKT] = p[t];   // == NED
}

// ---------------- bin edges by bucket into tmp (packed tgt<<32|src) ----------------
__global__ __launch_bounds__(256) void k_bscatter(const int2* __restrict__ e, int* __restrict__ gtail,
                                                  long long* __restrict__ tmp) {
    __shared__ int cnt[NBKT], chunk[NBKT], cur[NBKT];
    const int T = 4096;
    int ntile = (NED + T - 1) / T;
    for (int tile = blockIdx.x; tile < ntile; tile += gridDim.x) {
        int base = tile * T;
        int t = threadIdx.x;
        for (int i = t; i < NBKT; i += 256) { cnt[i] = 0; cur[i] = 0; }
        __syncthreads();
        int2 ed[16]; int bk[16];
#pragma unroll
        for (int i = 0; i < 16; i++) {
            int idx = base + i * 256 + t;
            if (idx < NED) {
                ed[i] = e[idx];
                bk[i] = ((unsigned)ed[i].y) >> BSH;
                atomicAdd(&cnt[bk[i]], 1);
            } else bk[i] = -1;
        }
        __syncthreads();
        for (int i = t; i < NBKT; i += 256) if (cnt[i]) chunk[i] = atomicAdd(&gtail[i], cnt[i]);
        __syncthreads();
#pragma unroll
        for (int i = 0; i < 16; i++) {
            if (bk[i] >= 0) {
                int r = atomicAdd(&cur[bk[i]], 1);
                tmp[(size_t)chunk[bk[i]] + r] =
                    ((long long)(unsigned)ed[i].y << 32) | (unsigned)ed[i].x;
            }
        }
        __syncthreads();
    }
}

// ---------------- per-bucket: degree hist + scan -> row, place srcs (single-CU window) ----------------
__global__ __launch_bounds__(512) void k_bfinish(const long long* __restrict__ tmp, const int* __restrict__ bbase,
                                                 int* __restrict__ row, int* __restrict__ srcs) {
    __shared__ int ld[512];
    __shared__ int lcur[512];
    int b = blockIdx.x, t = threadIdx.x;
    int node0 = b << BSH;
    int nn = min(512, NND - node0);
    int ebase = bbase[b], eend = bbase[b + 1];
    ld[t] = 0;
    __syncthreads();
    for (int i = ebase + t; i < eend; i += 512) {
        int tgt = (int)(tmp[i] >> 32);
        atomicAdd(&ld[tgt - node0], 1);
    }
    __syncthreads();
    int v = ld[t];
    for (int off = 1; off < 512; off <<= 1) {
        int u = (t >= off) ? ld[t - off] : 0;
        __syncthreads();
        ld[t] += u;
        __syncthreads();
    }
    int exc = ld[t] - v;             // exclusive prefix of degrees
    if (t < nn) row[node0 + t] = ebase + exc;
    lcur[t] = exc;
    __syncthreads();
    for (int i = ebase + t; i < eend; i += 512) {
        long long pk = tmp[i];
        int tgt = (int)(pk >> 32);
        int src = (int)(pk & 0xffffffffll);
        int p = atomicAdd(&lcur[tgt - node0], 1);
        srcs[ebase + p] = src;
    }
    if (b == NBKT - 1 && t == 0) row[NND] = NED;
}

// ---------------- prep: pre-swizzle weights into MFMA B-fragment layout (bf16) ----------------
__global__ void k_prep(const float* __restrict__ msg_w, const float* __restrict__ upd_w,
                       short* __restrict__ wmsg, short* __restrict__ wupd) {
    int t = blockIdx.x * blockDim.x + threadIdx.x;
    if (t >= 2 * NLAY * 8192) return;
    int which = t / (NLAY * 8192);
    int e = t % (NLAY * 8192);
    int l = e >> 13, idx = e & 8191;
    int j = idx & 7, lane = (idx >> 3) & 63, hi = idx >> 9;
    int lm = lane & 15, quad = lane >> 4;
    if (which == 0) {
        int ks = hi & 1, nt = hi >> 1;
        int n = nt * 16 + lm, k = ks * 32 + quad * 8 + j;
        float v = (n < 64) ? msg_w[(size_t)l * 8192 + k * 64 + n]
                           : msg_w[(size_t)l * 8192 + (64 + k) * 64 + (n - 64)];
        wmsg[e] = f2bf(v);
    } else {
        int ks = hi & 3, nt = hi >> 2;
        int n = nt * 16 + lm, k = ks * 32 + quad * 8 + j;
        wupd[e] = f2bf(upd_w[(size_t)l * 8192 + k * 64 + n]);
    }
}

// ---------------- P16 = half(x@Ws) ; Q = x@Wt + b  (MFMA, wave = 16 nodes x 128 cols) ----------------
__global__ __launch_bounds__(256) void k_pq(const float* __restrict__ x, const short* __restrict__ wb,
                                            const float* __restrict__ bg,
                                            __half* __restrict__ P16, float* __restrict__ Q) {
    int wv = threadIdx.x >> 6, lane = threadIdx.x & 63;
    int lm = lane & 15, quad = lane >> 4;
    int gmbase = blockIdx.x * 64 + wv * 16;
    int m = gmbase + lm;
    short8 a[2];
#pragma unroll
    for (int ks = 0; ks < 2; ks++) {
        float xv[8];
        if (m < NND) {
            float4 v0 = *(const float4*)(x + (size_t)m * 64 + ks * 32 + quad * 8);
            float4 v1 = *(const float4*)(x + (size_t)m * 64 + ks * 32 + quad * 8 + 4);
            xv[0] = v0.x; xv[1] = v0.y; xv[2] = v0.z; xv[3] = v0.w;
            xv[4] = v1.x; xv[5] = v1.y; xv[6] = v1.z; xv[7] = v1.w;
        } else {
#pragma unroll
            for (int j = 0; j < 8; j++) xv[j] = 0.f;
        }
        short8 av;
#pragma unroll
        for (int j = 0; j < 8; j++) av[j] = f2bf(xv[j]);
        a[ks] = av;
    }
    floatx4 acc[8];
#pragma unroll
    for (int nt = 0; nt < 8; nt++) acc[nt] = (floatx4){0.f, 0.f, 0.f, 0.f};
#pragma unroll
    for (int nt = 0; nt < 8; nt++) {
        short8 b0 = *(const short8*)(wb + (size_t)((nt * 2 + 0) * 64 + lane) * 8);
        short8 b1 = *(const short8*)(wb + (size_t)((nt * 2 + 1) * 64 + lane) * 8);
        acc[nt] = __builtin_amdgcn_mfma_f32_16x16x32_bf16(a[0], b0, acc[nt], 0, 0, 0);
        acc[nt] = __builtin_amdgcn_mfma_f32_16x16x32_bf16(a[1], b1, acc[nt], 0, 0, 0);
    }
    float bq[4];
#pragma unroll
    for (int nt = 0; nt < 4; nt++) bq[nt] = bg[nt * 16 + lm];
#pragma unroll
    for (int reg = 0; reg < 4; reg++) {
        int gn = gmbase + quad * 4 + reg;
        if (gn < NND) {
#pragma unroll
            for (int nt = 0; nt < 4; nt++)
                P16[(size_t)gn * 64 + nt * 16 + lm] = __float2half(acc[nt][reg]);
#pragma unroll
            for (int nt = 4; nt < 8; nt++)
                Q[(size_t)gn * 64 + (nt - 4) * 16 + lm] = acc[nt][reg] + bq[nt - 4];
        }
    }
}

// ---------------- aggregation: wave per node, 2 edges/iter, fp16 P gather ----------------
__global__ __launch_bounds__(256) void k_agg(const __half* __restrict__ P16, const float* __restrict__ Q,
                                             const int* __restrict__ row, const int* __restrict__ srcs,
                                             float* __restrict__ agg) {
    int wid = (blockIdx.x * blockDim.x + threadIdx.x) >> 6;  // node id
    int lane = threadIdx.x & 63;
    if (wid >= NND) return;
    int sub = lane >> 5, f2 = lane & 31, j0 = 2 * f2;
    int beg = row[wid], end = row[wid + 1];
    float2 q = *(const float2*)(Q + (size_t)wid * 64 + j0);
    float a0 = 0.f, a1 = 0.f;
    for (int e0 = beg; e0 < end; e0 += 64) {
        int cnt = min(64, end - e0);
        int sv = (lane < cnt) ? srcs[e0 + lane] : 0;
        int pairs = (cnt + 1) >> 1;
        for (int i = 0; i < pairs; i++) {
            int ei = 2 * i + sub;
            if (ei < cnt) {
                int s = __shfl(sv, ei);
                __half2 hp = *(const __half2*)(P16 + (size_t)s * 64 + j0);
                float2 f = __half22float2(hp);
                a0 += fmaxf(f.x + q.x, 0.f);
                a1 += fmaxf(f.y + q.y, 0.f);
            }
        }
    }
    a0 += __shfl_xor(a0, 32);
    a1 += __shfl_xor(a1, 32);
    if (sub == 0) {
        float inv = 1.f / fmaxf((float)(end - beg), 1.f);
        *(float2*)(agg + (size_t)wid * 64 + j0) = make_float2(a0 * inv, a1 * inv);
    }
}

// ---------------- update: u=relu([x|agg]@W+b); x=LN(u+x)  (MFMA, wave = 16 nodes) ----------------
__global__ __launch_bounds__(256) void k_upd(float* __restrict__ x, const float* __restrict__ agg,
                                             const short* __restrict__ wb, const float* __restrict__ ub,
                                             const float* __restrict__ lg, const float* __restrict__ lb) {
    int wv = threadIdx.x >> 6, lane = threadIdx.x & 63;
    int lm = lane & 15, quad = lane >> 4;
    int gmbase = blockIdx.x * 64 + wv * 16;
    int m = gmbase + lm;
    short8 a[4];
#pragma unroll
    for (int ks = 0; ks < 4; ks++) {
        const float* src = (ks < 2) ? x : agg;
        int c0 = (ks & 1) * 32 + quad * 8;
        float xv[8];
        if (m < NND) {
            float4 v0 = *(const float4*)(src + (size_t)m * 64 + c0);
            float4 v1 = *(const float4*)(src + (size_t)m * 64 + c0 + 4);
            xv[0] = v0.x; xv[1] = v0.y; xv[2] = v0.z; xv[3] = v0.w;
            xv[4] = v1.x; xv[5] = v1.y; xv[6] = v1.z; xv[7] = v1.w;
        } else {
#pragma unroll
            for (int j = 0; j < 8; j++) xv[j] = 0.f;
        }
        short8 av;
#pragma unroll
        for (int j = 0; j < 8; j++) av[j] = f2bf(xv[j]);
        a[ks] = av;
    }
    floatx4 acc[4];
#pragma unroll
    for (int nt = 0; nt < 4; nt++) acc[nt] = (floatx4){0.f, 0.f, 0.f, 0.f};
#pragma unroll
    for (int nt = 0; nt < 4; nt++) {
#pragma unroll
        for (int ks = 0; ks < 4; ks++) {
            short8 b = *(const short8*)(wb + (size_t)((nt * 4 + ks) * 64 + lane) * 8);
            acc[nt] = __builtin_amdgcn_mfma_f32_16x16x32_bf16(a[ks], b, acc[nt], 0, 0, 0);
        }
    }
    float ubv[4], lgv[4], lbv[4];
#pragma unroll
    for (int nt = 0; nt < 4; nt++) {
        int col = nt * 16 + lm;
        ubv[nt] = ub[col]; lgv[nt] = lg[col]; lbv[nt] = lb[col];
    }
#pragma unroll
    for (int reg = 0; reg < 4; reg++) {
        int gn = gmbase + quad * 4 + reg;
        bool ok = gn < NND;
        float h[4];
#pragma unroll
        for (int nt = 0; nt < 4; nt++) {
            float xv = ok ? x[(size_t)gn * 64 + nt * 16 + lm] : 0.f;
            float u = fmaxf(acc[nt][reg] + ubv[nt], 0.f);
            h[nt] = u + xv;
        }
        float s1 = h[0] + h[1] + h[2] + h[3];
        float s2 = h[0] * h[0] + h[1] * h[1] + h[2] * h[2] + h[3] * h[3];
#pragma unroll
        for (int off = 1; off < 16; off *= 2) {
            s1 += __shfl_xor(s1, off);
            s2 += __shfl_xor(s2, off);
        }
        float mu = s1 * (1.f / 64.f);
        float var = s2 * (1.f / 64.f) - mu * mu;
        float rs = rsqrtf(var + LNEPS);
        if (ok) {
#pragma unroll
            for (int nt = 0; nt < 4; nt++)
                x[(size_t)gn * 64 + nt * 16 + lm] = (h[nt] - mu) * rs * lgv[nt] + lbv[nt];
        }
    }
}

// ---------------- final reduce: column mean + max ----------------
__global__ void k_reduce(const float* __restrict__ x, float* __restrict__ rsum, unsigned* __restrict__ rmax) {
    __shared__ float sb[256];
    __shared__ float mb[256];
    int t = threadIdx.x;
    int j = t & 63, g = t >> 6;
    float s = 0.f, m = -3.402823466e38f;
    for (int r = blockIdx.x * 4 + g; r < NND; r += gridDim.x * 4) {
        float v = x[r * 64 + j];
        s += v;
        m = fmaxf(m, v);
    }
    sb[t] = s; mb[t] = m; __syncthreads();
    if (t < 64) {
        s = sb[t] + sb[t + 64] + sb[t + 128] + sb[t + 192];
        m = fmaxf(fmaxf(mb[t], mb[t + 64]), fmaxf(mb[t + 128], mb[t + 192]));
        atomicAdd(&rsum[j], s);
        unsigned b = __float_as_uint(m);
        unsigned enc = (b & 0x80000000u) ? ~b : (b | 0x80000000u);
        atomicMax(&rmax[j], enc);
    }
}

__global__ void k_fin(const float* __restrict__ rsum, const unsigned* __restrict__ rmax, float* __restrict__ out) {
    int t = threadIdx.x;
    if (t < 64) {
        out[t] = rsum[t] * (1.f / (float)NND);
    } else if (t < 128) {
        unsigned u = rmax[t - 64];
        unsigned b = (u & 0x80000000u) ? (u & 0x7fffffffu) : ~u;
        out[t] = __uint_as_float(b);
    }
}

extern "C" void kernel_launch(void* const* d_in, const int* in_sizes, int n_in,
                              void* d_out, int out_size, void* d_ws, size_t ws_size,
                              hipStream_t stream) {
    const int* ty      = (const int*)d_in[0];
    const int* ed      = (const int*)d_in[1];
    const float* tab   = (const float*)d_in[2];
    const float* msg_w = (const float*)d_in[3];
    const float* msg_b = (const float*)d_in[4];
    const float* upd_w = (const float*)d_in[5];
    const float* upd_b = (const float*)d_in[6];
    const float* ln_g  = (const float*)d_in[7];
    const float* ln_b  = (const float*)d_in[8];
    float* out = (float*)d_out;

    char* w = (char*)d_ws;
    auto alloc = [&](size_t sz) { char* p = w; w += (sz + 255) & ~(size_t)255; return p; };
    float* x       = (float*)alloc((size_t)NND * 64 * 4);
    float* Q       = (float*)alloc((size_t)NND * 64 * 4);
    float* agg     = (float*)alloc((size_t)NND * 64 * 4);
    __half* P16    = (__half*)alloc((size_t)NND * 64 * 2);
    long long* tmp = (long long*)alloc((size_t)NED * 8);
    int* row       = (int*)alloc((size_t)(NND + 1) * 4);
    int* srcs      = (int*)alloc((size_t)NED * 4);
    int* bcnt      = (int*)alloc(256 * 4);
    int* bbase     = (int*)alloc(256 * 4);
    int* gtail     = (int*)alloc(256 * 4);
    float* rsum    = (float*)alloc(64 * 4);
    unsigned* rmax = (unsigned*)alloc(64 * 4);
    short* wmsg    = (short*)alloc((size_t)NLAY * 8192 * 2);
    short* wupd    = (short*)alloc((size_t)NLAY * 8192 * 2);

    k_init<<<2, 256, 0, stream>>>(bcnt, rsum, rmax);
    k_prep<<<(2 * NLAY * 8192 + 255) / 256, 256, 0, stream>>>(msg_w, upd_w, wmsg, wupd);
    k_embed<<<(NND * 16 + 255) / 256, 256, 0, stream>>>(ty, (const float4*)tab, (float4*)x);
    k_bhist<<<256, 256, 0, stream>>>((const int2*)ed, bcnt);
    k_bbase<<<1, 256, 0, stream>>>(bcnt, bbase, gtail);
    k_bscatter<<<(NED + 4095) / 4096, 256, 0, stream>>>((const int2*)ed, gtail, tmp);
    k_bfinish<<<NBKT, 512, 0, stream>>>(tmp, bbase, row, srcs);

    for (int l = 0; l < NLAY; l++) {
        k_pq<<<(NND + 63) / 64, 256, 0, stream>>>(x, wmsg + (size_t)l * 8192, msg_b + l * 64, P16, Q);
        k_agg<<<NND / 4, 256, 0, stream>>>(P16, Q, row, srcs, agg);
        k_upd<<<(NND + 63) / 64, 256, 0, stream>>>(x, agg, wupd + (size_t)l * 8192,
                                                   upd_b + l * 64, ln_g + l * 64, ln_b + l * 64);
    }
    k_reduce<<<256, 256, 0, stream>>>(x, rsum, rmax);
    k_fin<<<1, 128, 0, stream>>>(rsum, rmax, out);
}

// Round 5
// 388.399 us; speedup vs baseline: 8.6435x; 1.0056x over previous
//
#include <hip/hip_runtime.h>
#include <hip/hip_fp16.h>
#include <math.h>

#define NND 100000
#define NED 800000
#define NLAY 3
#define BSH 9                      // 512 nodes per bucket
#define NBKT ((NND + 511) / 512)   // 196
static constexpr float LNEPS = 1e-5f;

typedef __attribute__((ext_vector_type(8))) short short8;
typedef __attribute__((ext_vector_type(4))) float floatx4;

// fp32 -> bf16 round-to-nearest-even
__device__ __forceinline__ short f2bf(float f) {
    unsigned u = __float_as_uint(f);
    u += 0x7fffu + ((u >> 16) & 1u);
    return (short)(u >> 16);
}

// unpack 8 consecutive halfs (16B) into fp32
__device__ __forceinline__ void load_h8(const __half* p, float* f) {
    uint4 v = *(const uint4*)p;
    unsigned a[4] = {v.x, v.y, v.z, v.w};
#pragma unroll
    for (int k = 0; k < 4; k++) {
        __half2 h = *(__half2*)&a[k];
        float2 g = __half22float2(h);
        f[2 * k] = g.x; f[2 * k + 1] = g.y;
    }
}

// ---------------- init: zero bucket counts + reduction accumulators ----------------
__global__ void k_init(int* __restrict__ bcnt, float* __restrict__ rsum, unsigned* __restrict__ rmax) {
    int gt = blockIdx.x * blockDim.x + threadIdx.x;
    if (gt < NBKT) bcnt[gt] = 0;
    if (gt >= 256 && gt < 320) { rsum[gt - 256] = 0.f; rmax[gt - 256] = 0u; }
}

// ---------------- embed: x[n] = table[type[n]] ----------------
__global__ void k_embed(const int* __restrict__ ty, const float4* __restrict__ tab, float4* __restrict__ x) {
    int t = blockIdx.x * blockDim.x + threadIdx.x;  // one float4 per thread
    if (t >= NND * 16) return;
    int n = t >> 4, q = t & 15;
    x[t] = tab[ty[n] * 16 + q];
}

// ---------------- bucket histogram (LDS-staged, no random global atomics) ----------------
__global__ __launch_bounds__(256) void k_bhist(const int2* __restrict__ e, int* __restrict__ bcnt) {
    __shared__ int h[NBKT];
    for (int i = threadIdx.x; i < NBKT; i += 256) h[i] = 0;
    __syncthreads();
    int stride = gridDim.x * 256;
    for (int i = blockIdx.x * 256 + threadIdx.x; i < NED; i += stride)
        atomicAdd(&h[((unsigned)e[i].y) >> BSH], 1);
    __syncthreads();
    for (int i = threadIdx.x; i < NBKT; i += 256) if (h[i]) atomicAdd(&bcnt[i], h[i]);
}

// ---------------- scan bucket counts -> bucket bases + global tails ----------------
__global__ void k_bbase(const int* __restrict__ bcnt, int* __restrict__ bbase, int* __restrict__ gtail) {
    __shared__ int p[256];
    int t = threadIdx.x;
    int v = (t < NBKT) ? bcnt[t] : 0;
    p[t] = v; __syncthreads();
    for (int off = 1; off < 256; off <<= 1) {
        int u = (t >= off) ? p[t - off] : 0;
        __syncthreads();
        p[t] += u; __syncthreads();
    }
    if (t < NBKT) { int ex = p[t] - v; bbase[t] = ex; gtail[t] = ex; }
    if (t == NBKT - 1) bbase[NBKT] = p[t];   // == NED
}

// ---------------- bin edges by bucket into tmp (packed tgt<<32|src) ----------------
__global__ __launch_bounds__(256) void k_bscatter(const int2* __restrict__ e, int* __restrict__ gtail,
                                                  long long* __restrict__ tmp) {
    __shared__ int cnt[NBKT], chunk[NBKT], cur[NBKT];
    const int T = 4096;
    int ntile = (NED + T - 1) / T;
    for (int tile = blockIdx.x; tile < ntile; tile += gridDim.x) {
        int base = tile * T;
        int t = threadIdx.x;
        for (int i = t; i < NBKT; i += 256) { cnt[i] = 0; cur[i] = 0; }
        __syncthreads();
        int2 ed[16]; int bk[16];
#pragma unroll
        for (int i = 0; i < 16; i++) {
            int idx = base + i * 256 + t;
            if (idx < NED) {
                ed[i] = e[idx];
                bk[i] = ((unsigned)ed[i].y) >> BSH;
                atomicAdd(&cnt[bk[i]], 1);
            } else bk[i] = -1;
        }
        __syncthreads();
        for (int i = t; i < NBKT; i += 256) if (cnt[i]) chunk[i] = atomicAdd(&gtail[i], cnt[i]);
        __syncthreads();
#pragma unroll
        for (int i = 0; i < 16; i++) {
            if (bk[i] >= 0) {
                int r = atomicAdd(&cur[bk[i]], 1);
                tmp[(size_t)chunk[bk[i]] + r] =
                    ((long long)(unsigned)ed[i].y << 32) | (unsigned)ed[i].x;
            }
        }
        __syncthreads();
    }
}

// ---------------- per-bucket: degree hist + scan -> row, place srcs (single-CU window) ----------------
__global__ __launch_bounds__(512) void k_bfinish(const long long* __restrict__ tmp, const int* __restrict__ bbase,
                                                 int* __restrict__ row, int* __restrict__ srcs) {
    __shared__ int ld[512];
    __shared__ int lcur[512];
    int b = blockIdx.x, t = threadIdx.x;
    int node0 = b << BSH;
    int nn = min(512, NND - node0);
    int ebase = bbase[b], eend = bbase[b + 1];
    ld[t] = 0;
    __syncthreads();
    for (int i = ebase + t; i < eend; i += 512) {
        int tgt = (int)(tmp[i] >> 32);
        atomicAdd(&ld[tgt - node0], 1);
    }
    __syncthreads();
    int v = ld[t];
    for (int off = 1; off < 512; off <<= 1) {
        int u = (t >= off) ? ld[t - off] : 0;
        __syncthreads();
        ld[t] += u;
        __syncthreads();
    }
    int exc = ld[t] - v;             // exclusive prefix of degrees
    if (t < nn) row[node0 + t] = ebase + exc;
    lcur[t] = exc;
    __syncthreads();
    for (int i = ebase + t; i < eend; i += 512) {
        long long pk = tmp[i];
        int tgt = (int)(pk >> 32);
        int src = (int)(pk & 0xffffffffll);
        int p = atomicAdd(&lcur[tgt - node0], 1);
        srcs[ebase + p] = src;
    }
    if (b == NBKT - 1 && t == 0) row[NND] = NED;
}

// ---------------- prep: pre-swizzle weights into MFMA B-fragment layout (bf16) ----------------
__global__ void k_prep(const float* __restrict__ msg_w, const float* __restrict__ upd_w,
                       short* __restrict__ wmsg, short* __restrict__ wupd) {
    int t = blockIdx.x * blockDim.x + threadIdx.x;
    if (t >= 2 * NLAY * 8192) return;
    int which = t / (NLAY * 8192);
    int e = t % (NLAY * 8192);
    int l = e >> 13, idx = e & 8191;
    int j = idx & 7, lane = (idx >> 3) & 63, hi = idx >> 9;
    int lm = lane & 15, quad = lane >> 4;
    if (which == 0) {
        int ks = hi & 1, nt = hi >> 1;
        int n = nt * 16 + lm, k = ks * 32 + quad * 8 + j;
        float v = (n < 64) ? msg_w[(size_t)l * 8192 + k * 64 + n]
                           : msg_w[(size_t)l * 8192 + (64 + k) * 64 + (n - 64)];
        wmsg[e] = f2bf(v);
    } else {
        int ks = hi & 3, nt = hi >> 2;
        int n = nt * 16 + lm, k = ks * 32 + quad * 8 + j;
        wupd[e] = f2bf(upd_w[(size_t)l * 8192 + k * 64 + n]);
    }
}

// ---------------- P16 = half(x@Ws) ; Q16 = half(x@Wt + b)  (MFMA, wave = 16 nodes x 128 cols) ----------------
__global__ __launch_bounds__(256) void k_pq(const float* __restrict__ x, const short* __restrict__ wb,
                                            const float* __restrict__ bg,
                                            __half* __restrict__ P16, __half* __restrict__ Q16) {
    int wv = threadIdx.x >> 6, lane = threadIdx.x & 63;
    int lm = lane & 15, quad = lane >> 4;
    int gmbase = blockIdx.x * 64 + wv * 16;
    int m = gmbase + lm;
    short8 a[2];
#pragma unroll
    for (int ks = 0; ks < 2; ks++) {
        float xv[8];
        if (m < NND) {
            float4 v0 = *(const float4*)(x + (size_t)m * 64 + ks * 32 + quad * 8);
            float4 v1 = *(const float4*)(x + (size_t)m * 64 + ks * 32 + quad * 8 + 4);
            xv[0] = v0.x; xv[1] = v0.y; xv[2] = v0.z; xv[3] = v0.w;
            xv[4] = v1.x; xv[5] = v1.y; xv[6] = v1.z; xv[7] = v1.w;
        } else {
#pragma unroll
            for (int j = 0; j < 8; j++) xv[j] = 0.f;
        }
        short8 av;
#pragma unroll
        for (int j = 0; j < 8; j++) av[j] = f2bf(xv[j]);
        a[ks] = av;
    }
    floatx4 acc[8];
#pragma unroll
    for (int nt = 0; nt < 8; nt++) acc[nt] = (floatx4){0.f, 0.f, 0.f, 0.f};
#pragma unroll
    for (int nt = 0; nt < 8; nt++) {
        short8 b0 = *(const short8*)(wb + (size_t)((nt * 2 + 0) * 64 + lane) * 8);
        short8 b1 = *(const short8*)(wb + (size_t)((nt * 2 + 1) * 64 + lane) * 8);
        acc[nt] = __builtin_amdgcn_mfma_f32_16x16x32_bf16(a[0], b0, acc[nt], 0, 0, 0);
        acc[nt] = __builtin_amdgcn_mfma_f32_16x16x32_bf16(a[1], b1, acc[nt], 0, 0, 0);
    }
    float bq[4];
#pragma unroll
    for (int nt = 0; nt < 4; nt++) bq[nt] = bg[nt * 16 + lm];
#pragma unroll
    for (int reg = 0; reg < 4; reg++) {
        int gn = gmbase + quad * 4 + reg;
        if (gn < NND) {
#pragma unroll
            for (int nt = 0; nt < 4; nt++)
                P16[(size_t)gn * 64 + nt * 16 + lm] = __float2half(acc[nt][reg]);
#pragma unroll
            for (int nt = 4; nt < 8; nt++)
                Q16[(size_t)gn * 64 + (nt - 4) * 16 + lm] = __float2half(acc[nt][reg] + bq[nt - 4]);
        }
    }
}

// ---------------- fused aggregate + update ----------------
// Phase 1: wave-per-16-nodes gather, 8 edges in flight (lane = sub*8+f8, 16B half8 loads),
//          mean into LDS tile aggs[64][68].
// Phase 2: MFMA update u=relu([x|agg]@W+b), x = LN(u+x), agg A-frags from LDS.
__global__ __launch_bounds__(256) void k_aggupd(float* __restrict__ x, const __half* __restrict__ P16,
                                                const __half* __restrict__ Q16,
                                                const int* __restrict__ row, const int* __restrict__ srcs,
                                                const short* __restrict__ wb, const float* __restrict__ ub,
                                                const float* __restrict__ lg, const float* __restrict__ lb) {
    __shared__ float aggs[64 * 68];
    int t = threadIdx.x, w = t >> 6, lane = t & 63;
    int sub = lane >> 3, f8 = lane & 7, j0 = f8 * 8;

    // ---- phase 1: gather ----
    for (int ln = 0; ln < 16; ln++) {
        int bn = w * 16 + ln;
        int wid = blockIdx.x * 64 + bn;
        float acc[8];
#pragma unroll
        for (int k = 0; k < 8; k++) acc[k] = 0.f;
        int beg = 0, end = 0;
        float qv[8];
        if (wid < NND) {
            beg = row[wid]; end = row[wid + 1];
            load_h8(Q16 + (size_t)wid * 64 + j0, qv);
        }
        for (int e0 = beg; e0 < end; e0 += 64) {
            int cnt = min(64, end - e0);
            int sv = (lane < cnt) ? srcs[e0 + lane] : 0;
            int iters = (cnt + 7) >> 3;
            for (int i = 0; i < iters; i++) {
                int ei = i * 8 + sub;
                if (ei < cnt) {
                    int s = __shfl(sv, ei);
                    float f[8];
                    load_h8(P16 + (size_t)s * 64 + j0, f);
#pragma unroll
                    for (int k = 0; k < 8; k++) acc[k] += fmaxf(f[k] + qv[k], 0.f);
                }
            }
        }
        // combine the 8 sub-groups (lane bits 3,4,5)
#pragma unroll
        for (int off = 8; off < 64; off <<= 1)
#pragma unroll
            for (int k = 0; k < 8; k++) acc[k] += __shfl_xor(acc[k], off);
        if (sub == 0) {
            float inv = 1.f / fmaxf((float)(end - beg), 1.f);
            float4 o0 = make_float4(acc[0] * inv, acc[1] * inv, acc[2] * inv, acc[3] * inv);
            float4 o1 = make_float4(acc[4] * inv, acc[5] * inv, acc[6] * inv, acc[7] * inv);
            *(float4*)(aggs + bn * 68 + j0) = o0;
            *(float4*)(aggs + bn * 68 + j0 + 4) = o1;
        }
    }
    __syncthreads();

    // ---- phase 2: MFMA update ----
    int lm = lane & 15, quad = lane >> 4;
    int gmbase = blockIdx.x * 64 + w * 16;
    int m = gmbase + lm;
    int bm = w * 16 + lm;
    short8 a[4];
#pragma unroll
    for (int ks = 0; ks < 2; ks++) {
        int c0 = ks * 32 + quad * 8;
        float xv[8];
        if (m < NND) {
            float4 v0 = *(const float4*)(x + (size_t)m * 64 + c0);
            float4 v1 = *(const float4*)(x + (size_t)m * 64 + c0 + 4);
            xv[0] = v0.x; xv[1] = v0.y; xv[2] = v0.z; xv[3] = v0.w;
            xv[4] = v1.x; xv[5] = v1.y; xv[6] = v1.z; xv[7] = v1.w;
        } else {
#pragma unroll
            for (int j = 0; j < 8; j++) xv[j] = 0.f;
        }
        short8 av;
#pragma unroll
        for (int j = 0; j < 8; j++) av[j] = f2bf(xv[j]);
        a[ks] = av;
    }
#pragma unroll
    for (int ks = 2; ks < 4; ks++) {
        const float* p = aggs + bm * 68 + (ks - 2) * 32 + quad * 8;
        float4 v0 = *(const float4*)p;
        float4 v1 = *(const float4*)(p + 4);
        float xv[8] = {v0.x, v0.y, v0.z, v0.w, v1.x, v1.y, v1.z, v1.w};
        short8 av;
#pragma unroll
        for (int j = 0; j < 8; j++) av[j] = f2bf(xv[j]);
        a[ks] = av;
    }
    floatx4 acc[4];
#pragma unroll
    for (int nt = 0; nt < 4; nt++) acc[nt] = (floatx4){0.f, 0.f, 0.f, 0.f};
#pragma unroll
    for (int nt = 0; nt < 4; nt++) {
#pragma unroll
        for (int ks = 0; ks < 4; ks++) {
            short8 b = *(const short8*)(wb + (size_t)((nt * 4 + ks) * 64 + lane) * 8);
            acc[nt] = __builtin_amdgcn_mfma_f32_16x16x32_bf16(a[ks], b, acc[nt], 0, 0, 0);
        }
    }
    float ubv[4], lgv[4], lbv[4];
#pragma unroll
    for (int nt = 0; nt < 4; nt++) {
        int col = nt * 16 + lm;
        ubv[nt] = ub[col]; lgv[nt] = lg[col]; lbv[nt] = lb[col];
    }
#pragma unroll
    for (int reg = 0; reg < 4; reg++) {
        int gn = gmbase + quad * 4 + reg;
        bool ok = gn < NND;
        float h[4];
#pragma unroll
        for (int nt = 0; nt < 4; nt++) {
            float xv = ok ? x[(size_t)gn * 64 + nt * 16 + lm] : 0.f;
            float u = fmaxf(acc[nt][reg] + ubv[nt], 0.f);
            h[nt] = u + xv;
        }
        float s1 = h[0] + h[1] + h[2] + h[3];
        float s2 = h[0] * h[0] + h[1] * h[1] + h[2] * h[2] + h[3] * h[3];
#pragma unroll
        for (int off = 1; off < 16; off *= 2) {
            s1 += __shfl_xor(s1, off);
            s2 += __shfl_xor(s2, off);
        }
        float mu = s1 * (1.f / 64.f);
        float var = s2 * (1.f / 64.f) - mu * mu;
        float rs = rsqrtf(var + LNEPS);
        if (ok) {
#pragma unroll
            for (int nt = 0; nt < 4; nt++)
                x[(size_t)gn * 64 + nt * 16 + lm] = (h[nt] - mu) * rs * lgv[nt] + lbv[nt];
        }
    }
}

// ---------------- final reduce: column mean + max ----------------
__global__ void k_reduce(const float* __restrict__ x, float* __restrict__ rsum, unsigned* __restrict__ rmax) {
    __shared__ float sb[256];
    __shared__ float mb[256];
    int t = threadIdx.x;
    int j = t & 63, g = t >> 6;
    float s = 0.f, m = -3.402823466e38f;
    for (int r = blockIdx.x * 4 + g; r < NND; r += gridDim.x * 4) {
        float v = x[r * 64 + j];
        s += v;
        m = fmaxf(m, v);
    }
    sb[t] = s; mb[t] = m; __syncthreads();
    if (t < 64) {
        s = sb[t] + sb[t + 64] + sb[t + 128] + sb[t + 192];
        m = fmaxf(fmaxf(mb[t], mb[t + 64]), fmaxf(mb[t + 128], mb[t + 192]));
        atomicAdd(&rsum[j], s);
        unsigned b = __float_as_uint(m);
        unsigned enc = (b & 0x80000000u) ? ~b : (b | 0x80000000u);
        atomicMax(&rmax[j], enc);
    }
}

__global__ void k_fin(const float* __restrict__ rsum, const unsigned* __restrict__ rmax, float* __restrict__ out) {
    int t = threadIdx.x;
    if (t < 64) {
        out[t] = rsum[t] * (1.f / (float)NND);
    } else if (t < 128) {
        unsigned u = rmax[t - 64];
        unsigned b = (u & 0x80000000u) ? (u & 0x7fffffffu) : ~u;
        out[t] = __uint_as_float(b);
    }
}

extern "C" void kernel_launch(void* const* d_in, const int* in_sizes, int n_in,
                              void* d_out, int out_size, void* d_ws, size_t ws_size,
                              hipStream_t stream) {
    const int* ty      = (const int*)d_in[0];
    const int* ed      = (const int*)d_in[1];
    const float* tab   = (const float*)d_in[2];
    const float* msg_w = (const float*)d_in[3];
    const float* msg_b = (const float*)d_in[4];
    const float* upd_w = (const float*)d_in[5];
    const float* upd_b = (const float*)d_in[6];
    const float* ln_g  = (const float*)d_in[7];
    const float* ln_b  = (const float*)d_in[8];
    float* out = (float*)d_out;

    char* w = (char*)d_ws;
    auto alloc = [&](size_t sz) { char* p = w; w += (sz + 255) & ~(size_t)255; return p; };
    float* x       = (float*)alloc((size_t)NND * 64 * 4);
    __half* P16    = (__half*)alloc((size_t)NND * 64 * 2);
    __half* Q16    = (__half*)alloc((size_t)NND * 64 * 2);
    long long* tmp = (long long*)alloc((size_t)NED * 8);
    int* row       = (int*)alloc((size_t)(NND + 1) * 4);
    int* srcs      = (int*)alloc((size_t)NED * 4);
    int* bcnt      = (int*)alloc(256 * 4);
    int* bbase     = (int*)alloc(256 * 4);
    int* gtail     = (int*)alloc(256 * 4);
    float* rsum    = (float*)alloc(64 * 4);
    unsigned* rmax = (unsigned*)alloc(64 * 4);
    short* wmsg    = (short*)alloc((size_t)NLAY * 8192 * 2);
    short* wupd    = (short*)alloc((size_t)NLAY * 8192 * 2);

    k_init<<<2, 256, 0, stream>>>(bcnt, rsum, rmax);
    k_prep<<<(2 * NLAY * 8192 + 255) / 256, 256, 0, stream>>>(msg_w, upd_w, wmsg, wupd);
    k_embed<<<(NND * 16 + 255) / 256, 256, 0, stream>>>(ty, (const float4*)tab, (float4*)x);
    k_bhist<<<256, 256, 0, stream>>>((const int2*)ed, bcnt);
    k_bbase<<<1, 256, 0, stream>>>(bcnt, bbase, gtail);
    k_bscatter<<<(NED + 4095) / 4096, 256, 0, stream>>>((const int2*)ed, gtail, tmp);
    k_bfinish<<<NBKT, 512, 0, stream>>>(tmp, bbase, row, srcs);

    for (int l = 0; l < NLAY; l++) {
        k_pq<<<(NND + 63) / 64, 256, 0, stream>>>(x, wmsg + (size_t)l * 8192, msg_b + l * 64, P16, Q16);
        k_aggupd<<<(NND + 63) / 64, 256, 0, stream>>>(x, P16, Q16, row, srcs,
                                                      wupd + (size_t)l * 8192,
                                                      upd_b + l * 64, ln_g + l * 64, ln_b + l * 64);
    }
    k_reduce<<<256, 256, 0, stream>>>(x, rsum, rmax);
    k_fin<<<1, 128, 0, stream>>>(rsum, rmax, out);
}

// Round 6
// 343.730 us; speedup vs baseline: 9.7668x; 1.1300x over previous
//
#include <hip/hip_runtime.h>
#include <hip/hip_fp16.h>
#include <math.h>

#define NND 100000
#define NED 800000
#define NLAY 3
#define BSH 9                      // 512 nodes per bucket
#define NBKT ((NND + 511) / 512)   // 196
static constexpr float LNEPS = 1e-5f;

typedef __attribute__((ext_vector_type(8))) short short8;
typedef __attribute__((ext_vector_type(4))) float floatx4;

// fp32 -> bf16 round-to-nearest-even
__device__ __forceinline__ short f2bf(float f) {
    unsigned u = __float_as_uint(f);
    u += 0x7fffu + ((u >> 16) & 1u);
    return (short)(u >> 16);
}

// unpack 8 consecutive halfs (16B) into fp32
__device__ __forceinline__ void load_h8(const __half* p, float* f) {
    uint4 v = *(const uint4*)p;
    unsigned a[4] = {v.x, v.y, v.z, v.w};
#pragma unroll
    for (int k = 0; k < 4; k++) {
        __half2 h = *(__half2*)&a[k];
        float2 g = __half22float2(h);
        f[2 * k] = g.x; f[2 * k + 1] = g.y;
    }
}

// ---------------- init: zero bucket counts + reduction accumulators ----------------
__global__ void k_init(int* __restrict__ bcnt, float* __restrict__ rsum, unsigned* __restrict__ rmax) {
    int gt = blockIdx.x * blockDim.x + threadIdx.x;
    if (gt < NBKT) bcnt[gt] = 0;
    if (gt >= 256 && gt < 320) { rsum[gt - 256] = 0.f; rmax[gt - 256] = 0u; }
}

// ---------------- embed: x[n] = table[type[n]] ----------------
__global__ void k_embed(const int* __restrict__ ty, const float4* __restrict__ tab, float4* __restrict__ x) {
    int t = blockIdx.x * blockDim.x + threadIdx.x;  // one float4 per thread
    if (t >= NND * 16) return;
    int n = t >> 4, q = t & 15;
    x[t] = tab[ty[n] * 16 + q];
}

// ---------------- bucket histogram (LDS-staged, no random global atomics) ----------------
__global__ __launch_bounds__(256) void k_bhist(const int2* __restrict__ e, int* __restrict__ bcnt) {
    __shared__ int h[NBKT];
    for (int i = threadIdx.x; i < NBKT; i += 256) h[i] = 0;
    __syncthreads();
    int stride = gridDim.x * 256;
    for (int i = blockIdx.x * 256 + threadIdx.x; i < NED; i += stride)
        atomicAdd(&h[((unsigned)e[i].y) >> BSH], 1);
    __syncthreads();
    for (int i = threadIdx.x; i < NBKT; i += 256) if (h[i]) atomicAdd(&bcnt[i], h[i]);
}

// ---------------- scan bucket counts -> bucket bases + global tails ----------------
__global__ void k_bbase(const int* __restrict__ bcnt, int* __restrict__ bbase, int* __restrict__ gtail) {
    __shared__ int p[256];
    int t = threadIdx.x;
    int v = (t < NBKT) ? bcnt[t] : 0;
    p[t] = v; __syncthreads();
    for (int off = 1; off < 256; off <<= 1) {
        int u = (t >= off) ? p[t - off] : 0;
        __syncthreads();
        p[t] += u; __syncthreads();
    }
    if (t < NBKT) { int ex = p[t] - v; bbase[t] = ex; gtail[t] = ex; }
    if (t == NBKT - 1) bbase[NBKT] = p[t];   // == NED
}

// ---------------- bin edges by bucket into tmp (packed tgt<<32|src) ----------------
__global__ __launch_bounds__(256) void k_bscatter(const int2* __restrict__ e, int* __restrict__ gtail,
                                                  long long* __restrict__ tmp) {
    __shared__ int cnt[NBKT], chunk[NBKT], cur[NBKT];
    const int T = 4096;
    int ntile = (NED + T - 1) / T;
    for (int tile = blockIdx.x; tile < ntile; tile += gridDim.x) {
        int base = tile * T;
        int t = threadIdx.x;
        for (int i = t; i < NBKT; i += 256) { cnt[i] = 0; cur[i] = 0; }
        __syncthreads();
        int2 ed[16]; int bk[16];
#pragma unroll
        for (int i = 0; i < 16; i++) {
            int idx = base + i * 256 + t;
            if (idx < NED) {
                ed[i] = e[idx];
                bk[i] = ((unsigned)ed[i].y) >> BSH;
                atomicAdd(&cnt[bk[i]], 1);
            } else bk[i] = -1;
        }
        __syncthreads();
        for (int i = t; i < NBKT; i += 256) if (cnt[i]) chunk[i] = atomicAdd(&gtail[i], cnt[i]);
        __syncthreads();
#pragma unroll
        for (int i = 0; i < 16; i++) {
            if (bk[i] >= 0) {
                int r = atomicAdd(&cur[bk[i]], 1);
                tmp[(size_t)chunk[bk[i]] + r] =
                    ((long long)(unsigned)ed[i].y << 32) | (unsigned)ed[i].x;
            }
        }
        __syncthreads();
    }
}

// ---------------- per-bucket: degree hist + scan -> row, place srcs (single-CU window) ----------------
__global__ __launch_bounds__(512) void k_bfinish(const long long* __restrict__ tmp, const int* __restrict__ bbase,
                                                 int* __restrict__ row, int* __restrict__ srcs) {
    __shared__ int ld[512];
    __shared__ int lcur[512];
    int b = blockIdx.x, t = threadIdx.x;
    int node0 = b << BSH;
    int nn = min(512, NND - node0);
    int ebase = bbase[b], eend = bbase[b + 1];
    ld[t] = 0;
    __syncthreads();
    for (int i = ebase + t; i < eend; i += 512) {
        int tgt = (int)(tmp[i] >> 32);
        atomicAdd(&ld[tgt - node0], 1);
    }
    __syncthreads();
    int v = ld[t];
    for (int off = 1; off < 512; off <<= 1) {
        int u = (t >= off) ? ld[t - off] : 0;
        __syncthreads();
        ld[t] += u;
        __syncthreads();
    }
    int exc = ld[t] - v;             // exclusive prefix of degrees
    if (t < nn) row[node0 + t] = ebase + exc;
    lcur[t] = exc;
    __syncthreads();
    for (int i = ebase + t; i < eend; i += 512) {
        long long pk = tmp[i];
        int tgt = (int)(pk >> 32);
        int src = (int)(pk & 0xffffffffll);
        int p = atomicAdd(&lcur[tgt - node0], 1);
        srcs[ebase + p] = src;
    }
    if (b == NBKT - 1 && t == 0) row[NND] = NED;
}

// ---------------- prep: pre-swizzle weights into MFMA B-fragment layout (bf16) ----------------
__global__ void k_prep(const float* __restrict__ msg_w, const float* __restrict__ upd_w,
                       short* __restrict__ wmsg, short* __restrict__ wupd) {
    int t = blockIdx.x * blockDim.x + threadIdx.x;
    if (t >= 2 * NLAY * 8192) return;
    int which = t / (NLAY * 8192);
    int e = t % (NLAY * 8192);
    int l = e >> 13, idx = e & 8191;
    int j = idx & 7, lane = (idx >> 3) & 63, hi = idx >> 9;
    int lm = lane & 15, quad = lane >> 4;
    if (which == 0) {
        int ks = hi & 1, nt = hi >> 1;
        int n = nt * 16 + lm, k = ks * 32 + quad * 8 + j;
        float v = (n < 64) ? msg_w[(size_t)l * 8192 + k * 64 + n]
                           : msg_w[(size_t)l * 8192 + (64 + k) * 64 + (n - 64)];
        wmsg[e] = f2bf(v);
    } else {
        int ks = hi & 3, nt = hi >> 2;
        int n = nt * 16 + lm, k = ks * 32 + quad * 8 + j;
        wupd[e] = f2bf(upd_w[(size_t)l * 8192 + k * 64 + n]);
    }
}

// ---------------- P16 = half(x@Ws) ; Q16 = half(x@Wt + b)  (MFMA + LDS-transposed 16B stores) ----------------
__global__ __launch_bounds__(256) void k_pq(const float* __restrict__ x, const short* __restrict__ wb,
                                            const float* __restrict__ bg,
                                            __half* __restrict__ P16, __half* __restrict__ Q16) {
    __shared__ __half outs[64 * 136];   // 64 nodes x 128 feats (P|Q), +8 pad halves -> 272B row stride
    int wv = threadIdx.x >> 6, lane = threadIdx.x & 63;
    int lm = lane & 15, quad = lane >> 4;
    int nbase = blockIdx.x * 64;
    int m = nbase + wv * 16 + lm;
    short8 a[2];
#pragma unroll
    for (int ks = 0; ks < 2; ks++) {
        float xv[8];
        if (m < NND) {
            float4 v0 = *(const float4*)(x + (size_t)m * 64 + ks * 32 + quad * 8);
            float4 v1 = *(const float4*)(x + (size_t)m * 64 + ks * 32 + quad * 8 + 4);
            xv[0] = v0.x; xv[1] = v0.y; xv[2] = v0.z; xv[3] = v0.w;
            xv[4] = v1.x; xv[5] = v1.y; xv[6] = v1.z; xv[7] = v1.w;
        } else {
#pragma unroll
            for (int j = 0; j < 8; j++) xv[j] = 0.f;
        }
        short8 av;
#pragma unroll
        for (int j = 0; j < 8; j++) av[j] = f2bf(xv[j]);
        a[ks] = av;
    }
    floatx4 acc[8];
#pragma unroll
    for (int nt = 0; nt < 8; nt++) acc[nt] = (floatx4){0.f, 0.f, 0.f, 0.f};
#pragma unroll
    for (int nt = 0; nt < 8; nt++) {
        short8 b0 = *(const short8*)(wb + (size_t)((nt * 2 + 0) * 64 + lane) * 8);
        short8 b1 = *(const short8*)(wb + (size_t)((nt * 2 + 1) * 64 + lane) * 8);
        acc[nt] = __builtin_amdgcn_mfma_f32_16x16x32_bf16(a[0], b0, acc[nt], 0, 0, 0);
        acc[nt] = __builtin_amdgcn_mfma_f32_16x16x32_bf16(a[1], b1, acc[nt], 0, 0, 0);
    }
    float bq[4];
#pragma unroll
    for (int nt = 0; nt < 4; nt++) bq[nt] = bg[nt * 16 + lm];
    // C/D layout -> LDS (P feats 0..63, Q feats 64..127)
#pragma unroll
    for (int reg = 0; reg < 4; reg++) {
        int rown = wv * 16 + quad * 4 + reg;
#pragma unroll
        for (int nt = 0; nt < 4; nt++)
            outs[rown * 136 + nt * 16 + lm] = __float2half(acc[nt][reg]);
#pragma unroll
        for (int nt = 4; nt < 8; nt++)
            outs[rown * 136 + 64 + (nt - 4) * 16 + lm] = __float2half(acc[nt][reg] + bq[nt - 4]);
    }
    __syncthreads();
    // contiguous 16B stores
    int t = threadIdx.x;
#pragma unroll
    for (int r = 0; r < 4; r++) {
        int s = r * 256 + t;            // 1024 segments of 16B
        int node = s >> 4, seg = s & 15;
        int gn = nbase + node;
        if (gn < NND) {
            uint4 v = *(const uint4*)(outs + node * 136 + seg * 8);
            __half* dst = (seg < 8) ? (P16 + (size_t)gn * 64 + seg * 8)
                                    : (Q16 + (size_t)gn * 64 + (seg - 8) * 8);
            *(uint4*)dst = v;
        }
    }
}

// ---------------- fused aggregate + update ----------------
// 512 threads / 64 nodes per block: 8 waves x 8 nodes serial in gather (latency hiding),
// then waves 0-3 do the MFMA update (u=relu([x|agg]@W+b), x=LN(u+x)) on 16-node tiles.
__global__ __launch_bounds__(512) void k_aggupd(float* __restrict__ x, const __half* __restrict__ P16,
                                                const __half* __restrict__ Q16,
                                                const int* __restrict__ row, const int* __restrict__ srcs,
                                                const short* __restrict__ wb, const float* __restrict__ ub,
                                                const float* __restrict__ lg, const float* __restrict__ lb) {
    __shared__ float aggs[64 * 68];
    int t = threadIdx.x, w = t >> 6, lane = t & 63;
    int sub = lane >> 3, f8 = lane & 7, j0 = f8 * 8;

    // ---- phase 1: gather (wave w owns nodes w*8 .. w*8+7) ----
    for (int ln = 0; ln < 8; ln++) {
        int bn = w * 8 + ln;
        int wid = blockIdx.x * 64 + bn;
        float acc[8];
#pragma unroll
        for (int k = 0; k < 8; k++) acc[k] = 0.f;
        int beg = 0, end = 0;
        float qv[8];
        if (wid < NND) {
            beg = row[wid]; end = row[wid + 1];
            load_h8(Q16 + (size_t)wid * 64 + j0, qv);
        }
        for (int e0 = beg; e0 < end; e0 += 64) {
            int cnt = min(64, end - e0);
            int sv = (lane < cnt) ? srcs[e0 + lane] : 0;
            int iters = (cnt + 7) >> 3;
            for (int i = 0; i < iters; i++) {
                int ei = i * 8 + sub;
                if (ei < cnt) {
                    int s = __shfl(sv, ei);
                    float f[8];
                    load_h8(P16 + (size_t)s * 64 + j0, f);
#pragma unroll
                    for (int k = 0; k < 8; k++) acc[k] += fmaxf(f[k] + qv[k], 0.f);
                }
            }
        }
#pragma unroll
        for (int off = 8; off < 64; off <<= 1)
#pragma unroll
            for (int k = 0; k < 8; k++) acc[k] += __shfl_xor(acc[k], off);
        if (sub == 0) {
            float inv = 1.f / fmaxf((float)(end - beg), 1.f);
            float4 o0 = make_float4(acc[0] * inv, acc[1] * inv, acc[2] * inv, acc[3] * inv);
            float4 o1 = make_float4(acc[4] * inv, acc[5] * inv, acc[6] * inv, acc[7] * inv);
            *(float4*)(aggs + bn * 68 + j0) = o0;
            *(float4*)(aggs + bn * 68 + j0 + 4) = o1;
        }
    }
    __syncthreads();

    // ---- phase 2: MFMA update (waves 0-3 only, 16 nodes each) ----
    if (w >= 4) return;
    int lm = lane & 15, quad = lane >> 4;
    int gmbase = blockIdx.x * 64 + w * 16;
    int m = gmbase + lm;
    int bm = w * 16 + lm;
    short8 a[4];
#pragma unroll
    for (int ks = 0; ks < 2; ks++) {
        int c0 = ks * 32 + quad * 8;
        float xv[8];
        if (m < NND) {
            float4 v0 = *(const float4*)(x + (size_t)m * 64 + c0);
            float4 v1 = *(const float4*)(x + (size_t)m * 64 + c0 + 4);
            xv[0] = v0.x; xv[1] = v0.y; xv[2] = v0.z; xv[3] = v0.w;
            xv[4] = v1.x; xv[5] = v1.y; xv[6] = v1.z; xv[7] = v1.w;
        } else {
#pragma unroll
            for (int j = 0; j < 8; j++) xv[j] = 0.f;
        }
        short8 av;
#pragma unroll
        for (int j = 0; j < 8; j++) av[j] = f2bf(xv[j]);
        a[ks] = av;
    }
#pragma unroll
    for (int ks = 2; ks < 4; ks++) {
        const float* p = aggs + bm * 68 + (ks - 2) * 32 + quad * 8;
        float4 v0 = *(const float4*)p;
        float4 v1 = *(const float4*)(p + 4);
        float xv[8] = {v0.x, v0.y, v0.z, v0.w, v1.x, v1.y, v1.z, v1.w};
        short8 av;
#pragma unroll
        for (int j = 0; j < 8; j++) av[j] = f2bf(xv[j]);
        a[ks] = av;
    }
    floatx4 acc[4];
#pragma unroll
    for (int nt = 0; nt < 4; nt++) acc[nt] = (floatx4){0.f, 0.f, 0.f, 0.f};
#pragma unroll
    for (int nt = 0; nt < 4; nt++) {
#pragma unroll
        for (int ks = 0; ks < 4; ks++) {
            short8 b = *(const short8*)(wb + (size_t)((nt * 4 + ks) * 64 + lane) * 8);
            acc[nt] = __builtin_amdgcn_mfma_f32_16x16x32_bf16(a[ks], b, acc[nt], 0, 0, 0);
        }
    }
    float ubv[4], lgv[4], lbv[4];
#pragma unroll
    for (int nt = 0; nt < 4; nt++) {
        int col = nt * 16 + lm;
        ubv[nt] = ub[col]; lgv[nt] = lg[col]; lbv[nt] = lb[col];
    }
#pragma unroll
    for (int reg = 0; reg < 4; reg++) {
        int gn = gmbase + quad * 4 + reg;
        bool ok = gn < NND;
        float h[4];
#pragma unroll
        for (int nt = 0; nt < 4; nt++) {
            float xv = ok ? x[(size_t)gn * 64 + nt * 16 + lm] : 0.f;
            float u = fmaxf(acc[nt][reg] + ubv[nt], 0.f);
            h[nt] = u + xv;
        }
        float s1 = h[0] + h[1] + h[2] + h[3];
        float s2 = h[0] * h[0] + h[1] * h[1] + h[2] * h[2] + h[3] * h[3];
#pragma unroll
        for (int off = 1; off < 16; off *= 2) {
            s1 += __shfl_xor(s1, off);
            s2 += __shfl_xor(s2, off);
        }
        float mu = s1 * (1.f / 64.f);
        float var = s2 * (1.f / 64.f) - mu * mu;
        float rs = rsqrtf(var + LNEPS);
        if (ok) {
#pragma unroll
            for (int nt = 0; nt < 4; nt++)
                x[(size_t)gn * 64 + nt * 16 + lm] = (h[nt] - mu) * rs * lgv[nt] + lbv[nt];
        }
    }
}

// ---------------- final reduce: column mean + max ----------------
__global__ void k_reduce(const float* __restrict__ x, float* __restrict__ rsum, unsigned* __restrict__ rmax) {
    __shared__ float sb[256];
    __shared__ float mb[256];
    int t = threadIdx.x;
    int j = t & 63, g = t >> 6;
    float s = 0.f, m = -3.402823466e38f;
    for (int r = blockIdx.x * 4 + g; r < NND; r += gridDim.x * 4) {
        float v = x[r * 64 + j];
        s += v;
        m = fmaxf(m, v);
    }
    sb[t] = s; mb[t] = m; __syncthreads();
    if (t < 64) {
        s = sb[t] + sb[t + 64] + sb[t + 128] + sb[t + 192];
        m = fmaxf(fmaxf(mb[t], mb[t + 64]), fmaxf(mb[t + 128], mb[t + 192]));
        atomicAdd(&rsum[j], s);
        unsigned b = __float_as_uint(m);
        unsigned enc = (b & 0x80000000u) ? ~b : (b | 0x80000000u);
        atomicMax(&rmax[j], enc);
    }
}

__global__ void k_fin(const float* __restrict__ rsum, const unsigned* __restrict__ rmax, float* __restrict__ out) {
    int t = threadIdx.x;
    if (t < 64) {
        out[t] = rsum[t] * (1.f / (float)NND);
    } else if (t < 128) {
        unsigned u = rmax[t - 64];
        unsigned b = (u & 0x80000000u) ? (u & 0x7fffffffu) : ~u;
        out[t] = __uint_as_float(b);
    }
}

extern "C" void kernel_launch(void* const* d_in, const int* in_sizes, int n_in,
                              void* d_out, int out_size, void* d_ws, size_t ws_size,
                              hipStream_t stream) {
    const int* ty      = (const int*)d_in[0];
    const int* ed      = (const int*)d_in[1];
    const float* tab   = (const float*)d_in[2];
    const float* msg_w = (const float*)d_in[3];
    const float* msg_b = (const float*)d_in[4];
    const float* upd_w = (const float*)d_in[5];
    const float* upd_b = (const float*)d_in[6];
    const float* ln_g  = (const float*)d_in[7];
    const float* ln_b  = (const float*)d_in[8];
    float* out = (float*)d_out;

    char* w = (char*)d_ws;
    auto alloc = [&](size_t sz) { char* p = w; w += (sz + 255) & ~(size_t)255; return p; };
    float* x       = (float*)alloc((size_t)NND * 64 * 4);
    __half* P16    = (__half*)alloc((size_t)NND * 64 * 2);
    __half* Q16    = (__half*)alloc((size_t)NND * 64 * 2);
    long long* tmp = (long long*)alloc((size_t)NED * 8);
    int* row       = (int*)alloc((size_t)(NND + 1) * 4);
    int* srcs      = (int*)alloc((size_t)NED * 4);
    int* bcnt      = (int*)alloc(256 * 4);
    int* bbase     = (int*)alloc(256 * 4);
    int* gtail     = (int*)alloc(256 * 4);
    float* rsum    = (float*)alloc(64 * 4);
    unsigned* rmax = (unsigned*)alloc(64 * 4);
    short* wmsg    = (short*)alloc((size_t)NLAY * 8192 * 2);
    short* wupd    = (short*)alloc((size_t)NLAY * 8192 * 2);

    k_init<<<2, 256, 0, stream>>>(bcnt, rsum, rmax);
    k_prep<<<(2 * NLAY * 8192 + 255) / 256, 256, 0, stream>>>(msg_w, upd_w, wmsg, wupd);
    k_embed<<<(NND * 16 + 255) / 256, 256, 0, stream>>>(ty, (const float4*)tab, (float4*)x);
    k_bhist<<<256, 256, 0, stream>>>((const int2*)ed, bcnt);
    k_bbase<<<1, 256, 0, stream>>>(bcnt, bbase, gtail);
    k_bscatter<<<(NED + 4095) / 4096, 256, 0, stream>>>((const int2*)ed, gtail, tmp);
    k_bfinish<<<NBKT, 512, 0, stream>>>(tmp, bbase, row, srcs);

    for (int l = 0; l < NLAY; l++) {
        k_pq<<<(NND + 63) / 64, 256, 0, stream>>>(x, wmsg + (size_t)l * 8192, msg_b + l * 64, P16, Q16);
        k_aggupd<<<(NND + 63) / 64, 512, 0, stream>>>(x, P16, Q16, row, srcs,
                                                      wupd + (size_t)l * 8192,
                                                      upd_b + l * 64, ln_g + l * 64, ln_b + l * 64);
    }
    k_reduce<<<256, 256, 0, stream>>>(x, rsum, rmax);
    k_fin<<<1, 128, 0, stream>>>(rsum, rmax, out);
}